// Round 13
// baseline (120.740 us; speedup 1.0000x reference)
//
#include <hip/hip_runtime.h>

// LocalAttention collapsed form, all-MFMA edition.
// folded[c,t,Y] = (1/36) sum_{c'} theta[c',t,Y] * sum_d cnt(d,Y) sum_r phi[c',r,Y+d]*g[c,r,Y+d]
// k_attn v7: PERSISTENT blocks (512 = 2/CU; XCD k owns image k; slot handles 3-4 tiles) with
// T14 register prefetch of next tile's phi/g/th issued under current tile's compute. All in-loop
// barriers are raw s_barrier + lgkmcnt(0) so prefetch vmcnt stays in flight across barriers.

typedef unsigned short u16;
typedef unsigned int u32;
using f32x4 = __attribute__((ext_vector_type(4))) float;
using bf16x8 = __attribute__((ext_vector_type(8))) short;

#define BB 8
#define TT 4
#define HH 56
#define HWD 3136
#define GROW 64          // padded g2 row length (u16)
#define GPLANE 3584      // 56*64 per (b,c,rho)
#define NTOT 100352.0f

__device__ __forceinline__ float bf_lo(u32 u) { return __uint_as_float(u << 16); }
__device__ __forceinline__ float bf_hi(u32 u) { return __uint_as_float(u & 0xffff0000u); }
__device__ __forceinline__ float bf16u(u16 u) { return __uint_as_float(((u32)u) << 16); }
__device__ __forceinline__ u16 f2bf(float f) {
  u32 u = __float_as_uint(f);
  u32 r = (u + 0x7fffu + ((u >> 16) & 1u)) >> 16;
  return (u16)r;
}
__device__ __forceinline__ u32 pack2(float a, float b) {
  return (u32)f2bf(a) | ((u32)f2bf(b) << 16);
}
__device__ __forceinline__ int imax(int a, int b) { return a > b ? a : b; }
__device__ __forceinline__ int imin(int a, int b) { return a < b ? a : b; }
__device__ __forceinline__ float cntf(int d, int p) {
  int lo = imax(-1, imax(-1 - d, p - (HH - 1)));
  int hi = imin(1, imin(1 - d, p));
  int n = hi - lo + 1;
  return n > 0 ? (float)n : 0.f;
}
// raw barrier: waits LDS only, leaves prefetch vmcnt in flight (m201-verified pattern)
__device__ __forceinline__ void bar_lgkm() {
  asm volatile("s_waitcnt lgkmcnt(0)" ::: "memory");
  __builtin_amdgcn_s_barrier();
}

// ---------------- K1: conv_in as bf16 MFMA GEMM (XCD-pinned: image b -> XCD b) ----------------
#define K1_XOFF 24576
__global__ __launch_bounds__(256, 4) void k_conv_in(const float* __restrict__ x,
                                                    const float* __restrict__ w_in,
                                                    const float* __restrict__ b_in,
                                                    u16* __restrict__ th, u16* __restrict__ ph,
                                                    u16* __restrict__ g2, float* __restrict__ stats) {
  __shared__ __align__(16) char sm[24576 + 8192];
  if (blockIdx.x == 0 && threadIdx.x < 128) stats[threadIdx.x] = 0.f;
  int bi0 = blockIdx.x;
  int bi = (bi0 & 7) * 196 + (bi0 >> 3);  // XCD k owns image b=k (1568 = 8*196)
  int bt = bi / 49, chunk = bi % 49;
  int b = bt >> 2, t = bt & 3;
  int p0 = chunk * 64;
  int tid = threadIdx.x;

#pragma unroll
  for (int it = 0; it < 12; ++it) {
    int task = it * 256 + tid;
    int o = task >> 4, c4 = (task & 15) * 4;
    float4 wv = *reinterpret_cast<const float4*>(&w_in[o * 64 + c4]);
    uint2 pv;
    pv.x = pack2(wv.x, wv.y);
    pv.y = pack2(wv.z, wv.w);
    *reinterpret_cast<uint2*>(sm + o * 128 + ((c4 * 2) ^ ((o & 7) << 4))) = pv;
  }
  const float* xb = x + ((size_t)b * 256 + t) * HWD + p0;
#pragma unroll
  for (int it = 0; it < 2; ++it) {
    int task = it * 256 + tid;
    int cp = task >> 4, p4 = task & 15;
    int c0 = cp * 2;
    float4 fa = *reinterpret_cast<const float4*>(&xb[(size_t)c0 * 4 * HWD + p4 * 4]);
    float4 fb = *reinterpret_cast<const float4*>(&xb[(size_t)(c0 + 1) * 4 * HWD + p4 * 4]);
    float va[4] = {fa.x, fa.y, fa.z, fa.w}, vb[4] = {fb.x, fb.y, fb.z, fb.w};
#pragma unroll
    for (int j = 0; j < 4; ++j) {
      int p = p4 * 4 + j;
      int slot = (p & 7) ^ ((p >> 2) & 7);
      *reinterpret_cast<u32*>(sm + K1_XOFF + p * 128 + ((c0 * 2) ^ (slot << 4))) = pack2(va[j], vb[j]);
    }
  }
  __syncthreads();

  int w = tid >> 6, lane = tid & 63, lr = lane & 15, lk = lane >> 4;
  f32x4 acc[3][4];
#pragma unroll
  for (int i = 0; i < 3; ++i)
#pragma unroll
    for (int n = 0; n < 4; ++n) acc[i][n] = (f32x4){0.f, 0.f, 0.f, 0.f};

#pragma unroll
  for (int kt = 0; kt < 2; ++kt) {
    bf16x8 af[3], bfr[4];
#pragma unroll
    for (int i = 0; i < 3; ++i) {
      int arow = (w * 3 + i) * 16 + lr;
      af[i] = *reinterpret_cast<const bf16x8*>(sm + arow * 128 + ((kt * 64 + lk * 16) ^ ((arow & 7) << 4)));
    }
#pragma unroll
    for (int n = 0; n < 4; ++n) {
      int brow = n * 16 + lr;
      int slot = (brow & 7) ^ ((brow >> 2) & 7);
      bfr[n] = *reinterpret_cast<const bf16x8*>(sm + K1_XOFF + brow * 128 + ((kt * 64 + lk * 16) ^ (slot << 4)));
    }
#pragma unroll
    for (int i = 0; i < 3; ++i)
#pragma unroll
      for (int n = 0; n < 4; ++n)
        acc[i][n] = __builtin_amdgcn_mfma_f32_16x16x32_bf16(af[i], bfr[n], acc[i][n], 0, 0, 0);
  }

#pragma unroll
  for (int i = 0; i < 3; ++i) {
    int mt = w * 3 + i;
    int ob = mt * 16 + lk * 4;
    int gsel = ob >> 6, o = ob & 63;
    float4 bv = *reinterpret_cast<const float4*>(&b_in[ob]);
    if (gsel < 2) {
      u16* og = gsel == 0 ? th : ph;
#pragma unroll
      for (int n = 0; n < 4; ++n) {
        int p = p0 + n * 16 + lr;
        f32x4 a = acc[i][n];
        uint2 v;
        v.x = pack2(a.x + bv.x, a.y + bv.y);
        v.y = pack2(a.z + bv.z, a.w + bv.w);
        *reinterpret_cast<uint2*>(&og[((size_t)bt * HWD + p) * 64 + o]) = v;
      }
    } else {
      // g: padded layout [b][c][t(rho)][y][64], xx = x + 2
      float bb[4] = {bv.x, bv.y, bv.z, bv.w};
      int y0p = p0 / 56;
      int rel0 = p0 - y0p * 56;
#pragma unroll
      for (int n = 0; n < 4; ++n) {
        f32x4 a = acc[i][n];
        float aa[4] = {a.x, a.y, a.z, a.w};
        int rel = rel0 + n * 16 + lr;           // <= 111
        int cnd = rel >= 56;
        int off = (y0p + cnd) * GROW + (rel - (cnd ? 56 : 0)) + 2;
#pragma unroll
        for (int r = 0; r < 4; ++r)
          g2[(((size_t)b * 64 + o + r) * 4 + t) * GPLANE + off] = f2bf(aa[r] + bb[r]);
      }
    }
  }
}

// ---------------- K2: MFMA attention v7 (persistent, prefetched) ----------------
#define PH_OFF 0
#define AS_OFF 0
#define G_OFF 32768
#define TH_OFF 65536
#define FOLD_OFF 65536
#define W_OFF 73728

__global__ __launch_bounds__(512, 4) void k_attn(const u16* __restrict__ th, const u16* __restrict__ ph,
                                                 const u16* __restrict__ g2,
                                                 const float* __restrict__ w_out,
                                                 const float* __restrict__ b_out,
                                                 u16* __restrict__ pre) {
  __shared__ __align__(16) char sm[81920];

  int tid = threadIdx.x;
  int w = tid >> 6, lane = tid & 63;
  int lr = lane & 15, lk = lane >> 4;
  int b = blockIdx.x & 7;       // XCD k owns image k
  int slot = blockIdx.x >> 3;   // 0..63; tiles slot, slot+64, slot+128 [, slot+192]

  uint4 pv[4], gv[4], thv;      // staging registers (all accesses statically unrolled)

  auto issue_loads = [&](int y0, int x0) {
#pragma unroll
    for (int s = 0; s < 4; ++s) {
      int task = s * 512 + tid;
      int row = task >> 3, ch = task & 7;
      int rho = row >> 6, Z = row & 63, zy = Z >> 3, zx = Z & 7;
      int Y = y0 - 2 + zy, X = x0 - 2 + zx;
      uint4 v = make_uint4(0, 0, 0, 0);
      if ((unsigned)Y < HH && (unsigned)X < HH)
        v = *reinterpret_cast<const uint4*>(&ph[(((size_t)b * 4 + rho) * HWD + Y * HH + X) * 64 + ch * 8]);
      pv[s] = v;
    }
#pragma unroll
    for (int s = 0; s < 4; ++s) {
      int task = s * 512 + tid;
      int c = task >> 5, rho = (task >> 3) & 3, zy = task & 7;
      int Y = y0 - 2 + zy;
      uint2 lo = make_uint2(0, 0), hi = make_uint2(0, 0);
      if ((unsigned)Y < HH) {
        const u16* gb = g2 + (((size_t)b * 64 + c) * 4 + rho) * GPLANE + Y * GROW + x0;
        lo = *reinterpret_cast<const uint2*>(gb);
        hi = *reinterpret_cast<const uint2*>(gb + 4);
      }
      gv[s] = make_uint4(lo.x, lo.y, hi.x, hi.y);
    }
    {
      int row = tid >> 3, ch = tid & 7;
      int pos = row >> 2, tau = row & 3;
      int Y = y0 + (pos >> 2), X = x0 + (pos & 3);
      thv = *reinterpret_cast<const uint4*>(&th[(((size_t)b * 4 + tau) * HWD + Y * HH + X) * 64 + ch * 8]);
    }
  };

  // prologue: issue first tile's loads, stage w_out once
  issue_loads((slot / 14) * 4, (slot % 14) * 4);
  {
    int o = tid >> 3, cg = tid & 7;
    float4 w0 = *reinterpret_cast<const float4*>(&w_out[o * 64 + cg * 8]);
    float4 w1 = *reinterpret_cast<const float4*>(&w_out[o * 64 + cg * 8 + 4]);
    uint4 wv = make_uint4(pack2(w0.x, w0.y), pack2(w0.z, w0.w), pack2(w1.x, w1.y), pack2(w1.z, w1.w));
    *reinterpret_cast<uint4*>(sm + W_OFF + o * 128 + ((cg * 16) ^ ((o & 7) << 4))) = wv;
  }

  for (int tile = slot; tile < 196; tile += 64) {
    int y0 = (tile / 14) * 4, x0 = (tile % 14) * 4;

    // ---- ds_write staged registers (compiler inserts vmcnt waits on pv/gv/thv) ----
#pragma unroll
    for (int s = 0; s < 4; ++s) {
      int task = s * 512 + tid;
      int row = task >> 3, ch = task & 7;
      *reinterpret_cast<uint4*>(sm + PH_OFF + row * 128 + ((ch * 16) ^ ((row & 7) << 4))) = pv[s];
    }
#pragma unroll
    for (int s = 0; s < 4; ++s) {
      int task = s * 512 + tid;
      int c = task >> 5, rho = (task >> 3) & 3, zy = task & 7;
      *reinterpret_cast<uint4*>(sm + G_OFF + c * 512 + ((16 * (rho * 8 + zy)) ^ ((c & 7) << 4))) = gv[s];
    }
    {
      int row = tid >> 3, ch = tid & 7;
      *reinterpret_cast<uint4*>(sm + TH_OFF + row * 128 + ((ch * 16) ^ ((row & 7) << 4))) = thv;
    }
    bar_lgkm();  // bar1: staged data visible

    // ---- issue NEXT tile's loads (latency hides under phases A-C) ----
    int ntile = tile + 64;
    if (ntile < 196) issue_loads((ntile / 14) * 4, (ntile % 14) * 4);

    // ---- Phase A: D[(rho,Z)][(pos,tau)] = phi . theta ----
    bf16x8 tb[4][2];
#pragma unroll
    for (int nt = 0; nt < 4; ++nt)
#pragma unroll
      for (int kt = 0; kt < 2; ++kt) {
        int row = nt * 16 + lr;
        tb[nt][kt] = *reinterpret_cast<const bf16x8*>(sm + TH_OFF + row * 128 + ((kt * 64 + lk * 16) ^ ((row & 7) << 4)));
      }
    f32x4 accA[2][4];
#pragma unroll
    for (int mi = 0; mi < 2; ++mi)
#pragma unroll
      for (int nt = 0; nt < 4; ++nt) accA[mi][nt] = (f32x4){0.f, 0.f, 0.f, 0.f};
    __builtin_amdgcn_s_setprio(1);
#pragma unroll
    for (int mi = 0; mi < 2; ++mi) {
      int mt = w * 2 + mi;
      int mrow = mt * 16 + lr;
      int p2 = (2 * mt) & 7;  // zy-pair start of this m-tile
#pragma unroll
      for (int kt = 0; kt < 2; ++kt) {
        bf16x8 af = *reinterpret_cast<const bf16x8*>(sm + PH_OFF + mrow * 128 + ((kt * 64 + lk * 16) ^ ((mrow & 7) << 4)));
#pragma unroll
        for (int nt = 0; nt < 4; ++nt) {
          if ((p2 == 0 && nt >= 2) || (p2 == 6 && nt < 2)) continue;  // cnt_y == 0 block
          accA[mi][nt] = __builtin_amdgcn_mfma_f32_16x16x32_bf16(af, tb[nt][kt], accA[mi][nt], 0, 0, 0);
        }
      }
    }
    __builtin_amdgcn_s_setprio(0);
    bar_lgkm();  // bar2: phi reads done; As may overwrite

    // ---- Phase A epilogue: ALU cnt, write As[(pos,tau)][(rho,Z)] ----
    {
      int px = lr >> 2;
#pragma unroll
      for (int mi = 0; mi < 2; ++mi) {
        int mbase = (w * 2 + mi) * 16 + lk * 4;
        int zy = (mbase >> 3) & 7;
        int zxb = mbase & 7;  // 0 or 4
        float cxv[4];
#pragma unroll
        for (int r = 0; r < 4; ++r) cxv[r] = cntf(zxb + r - 2 - px, x0 + px);
#pragma unroll
        for (int nt = 0; nt < 4; ++nt) {
          int n = nt * 16 + lr;
          float cyv = cntf(zy - 2 - nt, y0 + nt) * (1.f / 36.f);
          f32x4 a = accA[mi][nt];
          uint2 vv;
          vv.x = pack2(a.x * cyv * cxv[0], a.y * cyv * cxv[1]);
          vv.y = pack2(a.z * cyv * cxv[2], a.w * cyv * cxv[3]);
          *reinterpret_cast<uint2*>(sm + AS_OFF + n * 512 + ((mbase * 2) ^ ((n & 7) << 4))) = vv;
        }
      }
    }
    bar_lgkm();  // bar3: As ready

    // ---- Phase B: folded[(pos,tau)][c] = As * g ----
    int mtB = w & 3, ntb = (w >> 2) * 2;
    f32x4 accB[2];
    accB[0] = (f32x4){0.f, 0.f, 0.f, 0.f};
    accB[1] = (f32x4){0.f, 0.f, 0.f, 0.f};
    {
      int arow = mtB * 16 + lr;
      __builtin_amdgcn_s_setprio(1);
#pragma unroll
      for (int kt = 0; kt < 8; ++kt) {
        bf16x8 af = *reinterpret_cast<const bf16x8*>(sm + AS_OFF + arow * 512 + ((kt * 64 + lk * 16) ^ ((arow & 7) << 4)));
#pragma unroll
        for (int j = 0; j < 2; ++j) {
          int brow = (ntb + j) * 16 + lr;
          bf16x8 bfv = *reinterpret_cast<const bf16x8*>(sm + G_OFF + brow * 512 + ((kt * 64 + lk * 16) ^ ((brow & 7) << 4)));
          accB[j] = __builtin_amdgcn_mfma_f32_16x16x32_bf16(af, bfv, accB[j], 0, 0, 0);
        }
      }
      __builtin_amdgcn_s_setprio(0);
    }
    // write folded (bf16) into TH region (dead until next iter's th write, protected by bar5)
#pragma unroll
    for (int j = 0; j < 2; ++j) {
      int n = (ntb + j) * 16 + lr;
#pragma unroll
      for (int r = 0; r < 4; ++r) {
        int m = mtB * 16 + lk * 4 + r;
        *reinterpret_cast<u16*>(sm + FOLD_OFF + m * 128 + ((n * 2) ^ ((m & 7) << 4))) = f2bf(accB[j][r]);
      }
    }
    bar_lgkm();  // bar4: fold ready

    // ---- Phase C: pre[o][(pos,tau)] = W . fold^T ----
    int mtC = w & 3, ntc = (w >> 2) * 2;
    f32x4 accC[2];
    accC[0] = (f32x4){0.f, 0.f, 0.f, 0.f};
    accC[1] = (f32x4){0.f, 0.f, 0.f, 0.f};
    {
      int arow = mtC * 16 + lr;
      __builtin_amdgcn_s_setprio(1);
#pragma unroll
      for (int kt = 0; kt < 2; ++kt) {
        bf16x8 af = *reinterpret_cast<const bf16x8*>(sm + W_OFF + arow * 128 + ((kt * 64 + lk * 16) ^ ((arow & 7) << 4)));
#pragma unroll
        for (int j = 0; j < 2; ++j) {
          int brow = (ntc + j) * 16 + lr;
          bf16x8 bfv = *reinterpret_cast<const bf16x8*>(sm + FOLD_OFF + brow * 128 + ((kt * 64 + lk * 16) ^ ((brow & 7) << 4)));
          accC[j] = __builtin_amdgcn_mfma_f32_16x16x32_bf16(af, bfv, accC[j], 0, 0, 0);
        }
      }
      __builtin_amdgcn_s_setprio(0);
    }
    {
      int o = mtC * 16 + lk * 4;
      float4 bo = *reinterpret_cast<const float4*>(&b_out[o]);
#pragma unroll
      for (int j = 0; j < 2; ++j) {
        int n = (ntc + j) * 16 + lr;
        int pos = n >> 2, tau = n & 3;
        int hw = (y0 + (pos >> 2)) * HH + x0 + (pos & 3);
        uint2 v;
        v.x = pack2(accC[j].x + bo.x, accC[j].y + bo.y);
        v.y = pack2(accC[j].z + bo.z, accC[j].w + bo.w);
        *reinterpret_cast<uint2*>(&pre[(((size_t)b * 4 + tau) * HWD + hw) * 64 + o]) = v;
      }
    }
    bar_lgkm();  // bar5: FOLD/PH/G reads done before next iter's ds_writes
  }
}

// ---------------- K3: per-channel sum / sumsq of preBN (uint4 loads, XCD-pinned) ----------------
__global__ __launch_bounds__(256) void k_stats(const u16* __restrict__ pre, float* __restrict__ stats) {
  __shared__ float rs[32][64], qs[32][64];
  int tid = threadIdx.x;
  int bi0 = blockIdx.x;
  int bi = (bi0 & 7) * 49 + (bi0 >> 3);  // 392 = 8*49 -> XCD k reads image k's pre (L2-local)
  int og = tid & 7, pg = tid >> 3;
  const uint4* p128 = reinterpret_cast<const uint4*>(pre);
  size_t base = (size_t)bi * 256 + pg * 8;
  float s[8] = {0, 0, 0, 0, 0, 0, 0, 0}, q[8] = {0, 0, 0, 0, 0, 0, 0, 0};
#pragma unroll
  for (int j = 0; j < 8; ++j) {
    uint4 v = p128[(base + j) * 8 + og];
    u32 uu[4] = {v.x, v.y, v.z, v.w};
#pragma unroll
    for (int k = 0; k < 4; ++k) {
      float a = bf_lo(uu[k]), c = bf_hi(uu[k]);
      s[k * 2] += a; q[k * 2] += a * a;
      s[k * 2 + 1] += c; q[k * 2 + 1] += c * c;
    }
  }
#pragma unroll
  for (int k = 0; k < 8; ++k) {
    rs[pg][og * 8 + k] = s[k];
    qs[pg][og * 8 + k] = q[k];
  }
  __syncthreads();
  if (tid < 64) {
    float ts = 0.f, tq = 0.f;
#pragma unroll
    for (int g = 0; g < 32; ++g) { ts += rs[g][tid]; tq += qs[g][tid]; }
    atomicAdd(&stats[tid], ts);
    atomicAdd(&stats[64 + tid], tq);
  }
}

// ---------------- K4: BN finalize + residual (x prefetch, XCD-pinned pre reads) ----------------
__global__ __launch_bounds__(256) void k_final(const float* __restrict__ x, const u16* __restrict__ pre,
                                               const float* __restrict__ stats,
                                               const float* __restrict__ gamma,
                                               const float* __restrict__ beta,
                                               float* __restrict__ out) {
  __shared__ u32 pt[32][65];  // [c-pair][pos]; stride 65 dw == 1 mod 32 -> conflict-free
  int bi0 = blockIdx.x;
  int bi = (bi0 & 7) * 196 + (bi0 >> 3);  // XCD k owns image b=k (matches k_attn's pre writes)
  int bt = bi / 49, ck = bi % 49;
  int b = bt >> 2, t = bt & 3;
  int hw0 = ck * 64;
  int tid = threadIdx.x;
  int slot = tid & 15, c2 = tid >> 4;
  int p4 = slot * 4;

  // issue x loads EARLY (independent of the pre-transpose) so HBM latency hides under staging
  float4 xv[2][2];
  size_t xb[2][2];
#pragma unroll
  for (int half = 0; half < 2; ++half) {
    int c0 = (c2 + half * 16) * 2;
    xb[half][0] = ((size_t)(b * 64 + c0) * 4 + t) * HWD + hw0 + p4;
    xb[half][1] = xb[half][0] + 4 * HWD;
    xv[half][0] = *reinterpret_cast<const float4*>(&x[xb[half][0]]);
    xv[half][1] = *reinterpret_cast<const float4*>(&x[xb[half][1]]);
  }

  const u32* src = reinterpret_cast<const u32*>(pre) + ((size_t)bt * HWD + hw0) * 32;
#pragma unroll
  for (int it = 0; it < 8; ++it) {
    int task = it * 256 + tid;
    int p = task >> 5, cu = task & 31;
    pt[cu][p] = src[p * 32 + cu];
  }
  __syncthreads();
  const float invN = 1.f / NTOT;
#pragma unroll
  for (int half = 0; half < 2; ++half) {
    int cp = c2 + half * 16;
    int c0 = cp * 2;
    float mu0 = stats[c0] * invN;
    float va0 = stats[64 + c0] * invN - mu0 * mu0;
    float s0 = rsqrtf(va0 + 1e-5f) * gamma[c0];
    float h0 = beta[c0] - mu0 * s0;
    float mu1 = stats[c0 + 1] * invN;
    float va1 = stats[64 + c0 + 1] * invN - mu1 * mu1;
    float s1 = rsqrtf(va1 + 1e-5f) * gamma[c0 + 1];
    float h1 = beta[c0 + 1] - mu1 * s1;
    uint4 pv = *reinterpret_cast<const uint4*>(&pt[cp][p4]);
    float4 x0v = xv[half][0], x1v = xv[half][1];
    float4 o0, o1;
    o0.x = x0v.x + bf_lo(pv.x) * s0 + h0;  o1.x = x1v.x + bf_hi(pv.x) * s1 + h1;
    o0.y = x0v.y + bf_lo(pv.y) * s0 + h0;  o1.y = x1v.y + bf_hi(pv.y) * s1 + h1;
    o0.z = x0v.z + bf_lo(pv.z) * s0 + h0;  o1.z = x1v.z + bf_hi(pv.z) * s1 + h1;
    o0.w = x0v.w + bf_lo(pv.w) * s0 + h0;  o1.w = x1v.w + bf_hi(pv.w) * s1 + h1;
    *reinterpret_cast<float4*>(&out[xb[half][0]]) = o0;
    *reinterpret_cast<float4*>(&out[xb[half][1]]) = o1;
  }
}

extern "C" void kernel_launch(void* const* d_in, const int* in_sizes, int n_in,
                              void* d_out, int out_size, void* d_ws, size_t ws_size,
                              hipStream_t stream) {
  const float* x = (const float*)d_in[0];
  const float* w_in = (const float*)d_in[1];
  const float* b_in = (const float*)d_in[2];
  const float* w_out = (const float*)d_in[3];
  const float* b_out = (const float*)d_in[4];
  const float* gamma = (const float*)d_in[5];
  const float* beta = (const float*)d_in[6];
  float* out = (float*)d_out;

  const size_t NE = (size_t)BB * TT * HWD * 64;        // th/ph/pre
  const size_t NG = (size_t)BB * 64 * TT * GPLANE;     // padded g2
  u16* th = (u16*)d_ws;
  u16* ph = th + NE;
  u16* g2 = ph + NE;
  u16* pre = g2 + NG;
  float* stats = (float*)(pre + NE);

  k_conv_in<<<dim3(BB * TT * 49), dim3(256), 0, stream>>>(x, w_in, b_in, th, ph, g2, stats);
  k_attn<<<dim3(512), dim3(512), 0, stream>>>(th, ph, g2, w_out, b_out, pre);
  k_stats<<<dim3(392), dim3(256), 0, stream>>>(pre, stats);
  k_final<<<dim3(BB * TT * 49), dim3(256), 0, stream>>>(x, pre, stats, gamma, beta, out);
}

// Round 14
// 77.641 us; speedup vs baseline: 1.5551x; 1.5551x over previous
//
#include <hip/hip_runtime.h>

// LocalAttention collapsed form, all-MFMA edition. (Revert to round-10 best: 77.7 us.)
// folded[c,t,Y] = (1/36) sum_{c'} theta[c',t,Y] * sum_d cnt(d,Y) sum_r phi[c',r,Y+d]*g[c,r,Y+d]
// Cross-kernel XCD L2 affinity: all kernels swizzle blocks so image b lives on XCD b end-to-end.

typedef unsigned short u16;
typedef unsigned int u32;
using f32x4 = __attribute__((ext_vector_type(4))) float;
using bf16x8 = __attribute__((ext_vector_type(8))) short;

#define BB 8
#define TT 4
#define HH 56
#define HWD 3136
#define GROW 64          // padded g2 row length (u16)
#define GPLANE 3584      // 56*64 per (b,c,rho)
#define NTOT 100352.0f

__device__ __forceinline__ float bf_lo(u32 u) { return __uint_as_float(u << 16); }
__device__ __forceinline__ float bf_hi(u32 u) { return __uint_as_float(u & 0xffff0000u); }
__device__ __forceinline__ float bf16u(u16 u) { return __uint_as_float(((u32)u) << 16); }
__device__ __forceinline__ u16 f2bf(float f) {
  u32 u = __float_as_uint(f);
  u32 r = (u + 0x7fffu + ((u >> 16) & 1u)) >> 16;
  return (u16)r;
}
__device__ __forceinline__ u32 pack2(float a, float b) {
  return (u32)f2bf(a) | ((u32)f2bf(b) << 16);
}
__device__ __forceinline__ int imax(int a, int b) { return a > b ? a : b; }
__device__ __forceinline__ int imin(int a, int b) { return a < b ? a : b; }
__device__ __forceinline__ float cntf(int d, int p) {
  int lo = imax(-1, imax(-1 - d, p - (HH - 1)));
  int hi = imin(1, imin(1 - d, p));
  int n = hi - lo + 1;
  return n > 0 ? (float)n : 0.f;
}

// ---------------- K1: conv_in as bf16 MFMA GEMM (XCD-pinned: image b -> XCD b) ----------------
#define K1_XOFF 24576
__global__ __launch_bounds__(256, 4) void k_conv_in(const float* __restrict__ x,
                                                    const float* __restrict__ w_in,
                                                    const float* __restrict__ b_in,
                                                    u16* __restrict__ th, u16* __restrict__ ph,
                                                    u16* __restrict__ g2, float* __restrict__ stats) {
  __shared__ __align__(16) char sm[24576 + 8192];
  if (blockIdx.x == 0 && threadIdx.x < 128) stats[threadIdx.x] = 0.f;
  int bi0 = blockIdx.x;
  int bi = (bi0 & 7) * 196 + (bi0 >> 3);  // XCD k owns image b=k (1568 = 8*196)
  int bt = bi / 49, chunk = bi % 49;
  int b = bt >> 2, t = bt & 3;
  int p0 = chunk * 64;
  int tid = threadIdx.x;

#pragma unroll
  for (int it = 0; it < 12; ++it) {
    int task = it * 256 + tid;
    int o = task >> 4, c4 = (task & 15) * 4;
    float4 wv = *reinterpret_cast<const float4*>(&w_in[o * 64 + c4]);
    uint2 pv;
    pv.x = pack2(wv.x, wv.y);
    pv.y = pack2(wv.z, wv.w);
    *reinterpret_cast<uint2*>(sm + o * 128 + ((c4 * 2) ^ ((o & 7) << 4))) = pv;
  }
  const float* xb = x + ((size_t)b * 256 + t) * HWD + p0;
#pragma unroll
  for (int it = 0; it < 2; ++it) {
    int task = it * 256 + tid;
    int cp = task >> 4, p4 = task & 15;
    int c0 = cp * 2;
    float4 fa = *reinterpret_cast<const float4*>(&xb[(size_t)c0 * 4 * HWD + p4 * 4]);
    float4 fb = *reinterpret_cast<const float4*>(&xb[(size_t)(c0 + 1) * 4 * HWD + p4 * 4]);
    float va[4] = {fa.x, fa.y, fa.z, fa.w}, vb[4] = {fb.x, fb.y, fb.z, fb.w};
#pragma unroll
    for (int j = 0; j < 4; ++j) {
      int p = p4 * 4 + j;
      int slot = (p & 7) ^ ((p >> 2) & 7);
      *reinterpret_cast<u32*>(sm + K1_XOFF + p * 128 + ((c0 * 2) ^ (slot << 4))) = pack2(va[j], vb[j]);
    }
  }
  __syncthreads();

  int w = tid >> 6, lane = tid & 63, lr = lane & 15, lk = lane >> 4;
  f32x4 acc[3][4];
#pragma unroll
  for (int i = 0; i < 3; ++i)
#pragma unroll
    for (int n = 0; n < 4; ++n) acc[i][n] = (f32x4){0.f, 0.f, 0.f, 0.f};

#pragma unroll
  for (int kt = 0; kt < 2; ++kt) {
    bf16x8 af[3], bfr[4];
#pragma unroll
    for (int i = 0; i < 3; ++i) {
      int arow = (w * 3 + i) * 16 + lr;
      af[i] = *reinterpret_cast<const bf16x8*>(sm + arow * 128 + ((kt * 64 + lk * 16) ^ ((arow & 7) << 4)));
    }
#pragma unroll
    for (int n = 0; n < 4; ++n) {
      int brow = n * 16 + lr;
      int slot = (brow & 7) ^ ((brow >> 2) & 7);
      bfr[n] = *reinterpret_cast<const bf16x8*>(sm + K1_XOFF + brow * 128 + ((kt * 64 + lk * 16) ^ (slot << 4)));
    }
#pragma unroll
    for (int i = 0; i < 3; ++i)
#pragma unroll
      for (int n = 0; n < 4; ++n)
        acc[i][n] = __builtin_amdgcn_mfma_f32_16x16x32_bf16(af[i], bfr[n], acc[i][n], 0, 0, 0);
  }

#pragma unroll
  for (int i = 0; i < 3; ++i) {
    int mt = w * 3 + i;
    int ob = mt * 16 + lk * 4;
    int gsel = ob >> 6, o = ob & 63;
    float4 bv = *reinterpret_cast<const float4*>(&b_in[ob]);
    if (gsel < 2) {
      u16* og = gsel == 0 ? th : ph;
#pragma unroll
      for (int n = 0; n < 4; ++n) {
        int p = p0 + n * 16 + lr;
        f32x4 a = acc[i][n];
        uint2 v;
        v.x = pack2(a.x + bv.x, a.y + bv.y);
        v.y = pack2(a.z + bv.z, a.w + bv.w);
        *reinterpret_cast<uint2*>(&og[((size_t)bt * HWD + p) * 64 + o]) = v;
      }
    } else {
      // g: padded layout [b][c][t(rho)][y][64], xx = x + 2
      float bb[4] = {bv.x, bv.y, bv.z, bv.w};
      int y0p = p0 / 56;
      int rel0 = p0 - y0p * 56;
#pragma unroll
      for (int n = 0; n < 4; ++n) {
        f32x4 a = acc[i][n];
        float aa[4] = {a.x, a.y, a.z, a.w};
        int rel = rel0 + n * 16 + lr;           // <= 111
        int cnd = rel >= 56;
        int off = (y0p + cnd) * GROW + (rel - (cnd ? 56 : 0)) + 2;
#pragma unroll
        for (int r = 0; r < 4; ++r)
          g2[(((size_t)b * 64 + o + r) * 4 + t) * GPLANE + off] = f2bf(aa[r] + bb[r]);
      }
    }
  }
}

// ---------------- K2: MFMA attention (round-7 staged structure, unchanged) ----------------
#define PH_OFF 0
#define AS_OFF 0
#define G_OFF 32768
#define W_OFF 32768
#define TH_OFF 65536
#define FOLD_OFF 65536
#define TAB_OFF 73728

__global__ __launch_bounds__(512, 4) void k_attn(const u16* __restrict__ th, const u16* __restrict__ ph,
                                                 const u16* __restrict__ g2,
                                                 const float* __restrict__ w_out,
                                                 const float* __restrict__ b_out,
                                                 u16* __restrict__ pre) {
  __shared__ __align__(16) char sm[73984];

  // XCD-chunked swizzle: 1568 = 8*196 -> XCD k owns image b=k; halo re-reads are L2-local.
  int bi0 = blockIdx.x;
  int bi = (bi0 & 7) * 196 + (bi0 >> 3);
  int b = bi / 196, tile = bi % 196;
  int ty = tile / 14, tx = tile % 14;
  int y0 = ty * 4, x0 = tx * 4;
  int tid = threadIdx.x;
  int w = tid >> 6, lane = tid & 63;
  int lr = lane & 15, lk = lane >> 4;

  // stage phi: rows (rho,Z), cols c, swizzled
  for (int task = tid; task < 2048; task += 512) {
    int row = task >> 3, ch = task & 7;
    int rho = row >> 6, Z = row & 63, zy = Z >> 3, zx = Z & 7;
    int Y = y0 - 2 + zy, X = x0 - 2 + zx;
    uint4 v = make_uint4(0, 0, 0, 0);
    if ((unsigned)Y < HH && (unsigned)X < HH)
      v = *reinterpret_cast<const uint4*>(&ph[(((size_t)b * 4 + rho) * HWD + Y * HH + X) * 64 + ch * 8]);
    *reinterpret_cast<uint4*>(sm + PH_OFF + row * 128 + ((ch * 16) ^ ((row & 7) << 4))) = v;
  }
  // stage theta: rows (pos,tau)
  {
    int row = tid >> 3, ch = tid & 7;
    int pos = row >> 2, tau = row & 3;
    int Y = y0 + (pos >> 2), X = x0 + (pos & 3);
    uint4 v = *reinterpret_cast<const uint4*>(&th[(((size_t)b * 4 + tau) * HWD + Y * HH + X) * 64 + ch * 8]);
    *reinterpret_cast<uint4*>(sm + TH_OFF + row * 128 + ((ch * 16) ^ ((row & 7) << 4))) = v;
  }
  // stage g (padded layout): per (c,rho,zy) one aligned 16B chunk via 2x dwordx2
  for (int task = tid; task < 2048; task += 512) {
    int c = task >> 5, rho = (task >> 3) & 3, zy = task & 7;
    int Y = y0 - 2 + zy;
    uint2 lo = make_uint2(0, 0), hi = make_uint2(0, 0);
    if ((unsigned)Y < HH) {
      const u16* gb = g2 + (((size_t)b * 64 + c) * 4 + rho) * GPLANE + Y * GROW + x0;  // xx0 = (x0-2)+2
      lo = *reinterpret_cast<const uint2*>(gb);
      hi = *reinterpret_cast<const uint2*>(gb + 4);
    }
    uint4 v = make_uint4(lo.x, lo.y, hi.x, hi.y);
    *reinterpret_cast<uint4*>(sm + G_OFF + c * 512 + ((16 * (rho * 8 + zy)) ^ ((c & 7) << 4))) = v;
  }
  // cnt tables (1/36 folded into cyt)
  if (tid < 32) {
    int zy = tid >> 2, py = tid & 3;
    reinterpret_cast<float*>(sm + TAB_OFF)[tid] = cntf(zy - 2 - py, y0 + py) * (1.f / 36.f);
  } else if (tid < 64) {
    int i = tid - 32;
    int zx = i >> 2, px = i & 3;
    reinterpret_cast<float*>(sm + TAB_OFF + 128)[i] = cntf(zx - 2 - px, x0 + px);
  }
  __syncthreads();

  // ---- Phase A: D[(rho,Z)][(pos,tau)] = phi . theta ----
  bf16x8 tb[4][2];
#pragma unroll
  for (int nt = 0; nt < 4; ++nt)
#pragma unroll
    for (int kt = 0; kt < 2; ++kt) {
      int row = nt * 16 + lr;
      tb[nt][kt] = *reinterpret_cast<const bf16x8*>(sm + TH_OFF + row * 128 + ((kt * 64 + lk * 16) ^ ((row & 7) << 4)));
    }
  f32x4 accA[2][4];
#pragma unroll
  for (int mi = 0; mi < 2; ++mi)
#pragma unroll
    for (int nt = 0; nt < 4; ++nt) accA[mi][nt] = (f32x4){0.f, 0.f, 0.f, 0.f};
  __builtin_amdgcn_s_setprio(1);
#pragma unroll
  for (int mi = 0; mi < 2; ++mi) {
    int mt = w * 2 + mi;
    int mrow = mt * 16 + lr;
    int p2 = (2 * mt) & 7;  // zy-pair start of this m-tile
#pragma unroll
    for (int kt = 0; kt < 2; ++kt) {
      bf16x8 af = *reinterpret_cast<const bf16x8*>(sm + PH_OFF + mrow * 128 + ((kt * 64 + lk * 16) ^ ((mrow & 7) << 4)));
#pragma unroll
      for (int nt = 0; nt < 4; ++nt) {
        if ((p2 == 0 && nt >= 2) || (p2 == 6 && nt < 2)) continue;  // cnt_y == 0 block
        accA[mi][nt] = __builtin_amdgcn_mfma_f32_16x16x32_bf16(af, tb[nt][kt], accA[mi][nt], 0, 0, 0);
      }
    }
  }
  __builtin_amdgcn_s_setprio(0);
  __syncthreads();  // phi reads done; As may overwrite

  // ---- Phase A epilogue: scale by cnt (py=nt, px=lr>>2), write As[(pos,tau)][(rho,Z)] ----
  {
    const float* cyt = reinterpret_cast<const float*>(sm + TAB_OFF);
    const float* cxt = reinterpret_cast<const float*>(sm + TAB_OFF + 128);
    int px = lr >> 2;
#pragma unroll
    for (int mi = 0; mi < 2; ++mi) {
      int mbase = (w * 2 + mi) * 16 + lk * 4;
      int zy = (mbase >> 3) & 7;
      int zxb = mbase & 7;  // 0 or 4
      float cxv[4];
#pragma unroll
      for (int r = 0; r < 4; ++r) cxv[r] = cxt[(zxb + r) * 4 + px];
#pragma unroll
      for (int nt = 0; nt < 4; ++nt) {
        int n = nt * 16 + lr;
        float cyv = cyt[zy * 4 + nt];
        f32x4 a = accA[mi][nt];
        uint2 vv;
        vv.x = pack2(a.x * cyv * cxv[0], a.y * cyv * cxv[1]);
        vv.y = pack2(a.z * cyv * cxv[2], a.w * cyv * cxv[3]);
        *reinterpret_cast<uint2*>(sm + AS_OFF + n * 512 + ((mbase * 2) ^ ((n & 7) << 4))) = vv;
      }
    }
  }
  __syncthreads();  // As ready

  // ---- Phase B: folded[(pos,tau)][c] = As * g ----
  int mtB = w & 3, ntb = (w >> 2) * 2;
  f32x4 accB[2];
  accB[0] = (f32x4){0.f, 0.f, 0.f, 0.f};
  accB[1] = (f32x4){0.f, 0.f, 0.f, 0.f};
  {
    int arow = mtB * 16 + lr;
    __builtin_amdgcn_s_setprio(1);
#pragma unroll
    for (int kt = 0; kt < 8; ++kt) {
      bf16x8 af = *reinterpret_cast<const bf16x8*>(sm + AS_OFF + arow * 512 + ((kt * 64 + lk * 16) ^ ((arow & 7) << 4)));
#pragma unroll
      for (int j = 0; j < 2; ++j) {
        int brow = (ntb + j) * 16 + lr;
        bf16x8 bfv = *reinterpret_cast<const bf16x8*>(sm + G_OFF + brow * 512 + ((kt * 64 + lk * 16) ^ ((brow & 7) << 4)));
        accB[j] = __builtin_amdgcn_mfma_f32_16x16x32_bf16(af, bfv, accB[j], 0, 0, 0);
      }
    }
    __builtin_amdgcn_s_setprio(0);
  }
  __syncthreads();  // g reads done; w_s may overwrite

  // ---- write folded (bf16) + stage w_out ----
#pragma unroll
  for (int j = 0; j < 2; ++j) {
    int n = (ntb + j) * 16 + lr;
#pragma unroll
    for (int r = 0; r < 4; ++r) {
      int m = mtB * 16 + lk * 4 + r;
      *reinterpret_cast<u16*>(sm + FOLD_OFF + m * 128 + ((n * 2) ^ ((m & 7) << 4))) = f2bf(accB[j][r]);
    }
  }
  {
    int o = tid >> 3, cg = tid & 7;
    float4 w0 = *reinterpret_cast<const float4*>(&w_out[o * 64 + cg * 8]);
    float4 w1 = *reinterpret_cast<const float4*>(&w_out[o * 64 + cg * 8 + 4]);
    uint4 wv = make_uint4(pack2(w0.x, w0.y), pack2(w0.z, w0.w), pack2(w1.x, w1.y), pack2(w1.z, w1.w));
    *reinterpret_cast<uint4*>(sm + W_OFF + o * 128 + ((cg * 16) ^ ((o & 7) << 4))) = wv;
  }
  __syncthreads();

  // ---- Phase C: pre[o][(pos,tau)] = W . fold^T ----
  int mtC = w & 3, ntc = (w >> 2) * 2;
  f32x4 accC[2];
  accC[0] = (f32x4){0.f, 0.f, 0.f, 0.f};
  accC[1] = (f32x4){0.f, 0.f, 0.f, 0.f};
  {
    int arow = mtC * 16 + lr;
    __builtin_amdgcn_s_setprio(1);
#pragma unroll
    for (int kt = 0; kt < 2; ++kt) {
      bf16x8 af = *reinterpret_cast<const bf16x8*>(sm + W_OFF + arow * 128 + ((kt * 64 + lk * 16) ^ ((arow & 7) << 4)));
#pragma unroll
      for (int j = 0; j < 2; ++j) {
        int brow = (ntc + j) * 16 + lr;
        bf16x8 bfv = *reinterpret_cast<const bf16x8*>(sm + FOLD_OFF + brow * 128 + ((kt * 64 + lk * 16) ^ ((brow & 7) << 4)));
        accC[j] = __builtin_amdgcn_mfma_f32_16x16x32_bf16(af, bfv, accC[j], 0, 0, 0);
      }
    }
    __builtin_amdgcn_s_setprio(0);
  }
  {
    int o = mtC * 16 + lk * 4;
    float4 bo = *reinterpret_cast<const float4*>(&b_out[o]);
#pragma unroll
    for (int j = 0; j < 2; ++j) {
      int n = (ntc + j) * 16 + lr;
      int pos = n >> 2, tau = n & 3;
      int hw = (y0 + (pos >> 2)) * HH + x0 + (pos & 3);
      uint2 v;
      v.x = pack2(accC[j].x + bo.x, accC[j].y + bo.y);
      v.y = pack2(accC[j].z + bo.z, accC[j].w + bo.w);
      *reinterpret_cast<uint2*>(&pre[(((size_t)b * 4 + tau) * HWD + hw) * 64 + o]) = v;
    }
  }
}

// ---------------- K3: per-channel sum / sumsq of preBN (uint4 loads, XCD-pinned) ----------------
__global__ __launch_bounds__(256) void k_stats(const u16* __restrict__ pre, float* __restrict__ stats) {
  __shared__ float rs[32][64], qs[32][64];
  int tid = threadIdx.x;
  int bi0 = blockIdx.x;
  int bi = (bi0 & 7) * 49 + (bi0 >> 3);  // 392 = 8*49 -> XCD k reads image k's pre (L2-local)
  int og = tid & 7, pg = tid >> 3;
  const uint4* p128 = reinterpret_cast<const uint4*>(pre);
  size_t base = (size_t)bi * 256 + pg * 8;
  float s[8] = {0, 0, 0, 0, 0, 0, 0, 0}, q[8] = {0, 0, 0, 0, 0, 0, 0, 0};
#pragma unroll
  for (int j = 0; j < 8; ++j) {
    uint4 v = p128[(base + j) * 8 + og];
    u32 uu[4] = {v.x, v.y, v.z, v.w};
#pragma unroll
    for (int k = 0; k < 4; ++k) {
      float a = bf_lo(uu[k]), c = bf_hi(uu[k]);
      s[k * 2] += a; q[k * 2] += a * a;
      s[k * 2 + 1] += c; q[k * 2 + 1] += c * c;
    }
  }
#pragma unroll
  for (int k = 0; k < 8; ++k) {
    rs[pg][og * 8 + k] = s[k];
    qs[pg][og * 8 + k] = q[k];
  }
  __syncthreads();
  if (tid < 64) {
    float ts = 0.f, tq = 0.f;
#pragma unroll
    for (int g = 0; g < 32; ++g) { ts += rs[g][tid]; tq += qs[g][tid]; }
    atomicAdd(&stats[tid], ts);
    atomicAdd(&stats[64 + tid], tq);
  }
}

// ---------------- K4: BN finalize + residual (x prefetch, XCD-pinned pre reads) ----------------
__global__ __launch_bounds__(256) void k_final(const float* __restrict__ x, const u16* __restrict__ pre,
                                               const float* __restrict__ stats,
                                               const float* __restrict__ gamma,
                                               const float* __restrict__ beta,
                                               float* __restrict__ out) {
  __shared__ u32 pt[32][65];  // [c-pair][pos]; stride 65 dw == 1 mod 32 -> conflict-free
  int bi0 = blockIdx.x;
  int bi = (bi0 & 7) * 196 + (bi0 >> 3);  // XCD k owns image b=k (matches k_attn's pre writes)
  int bt = bi / 49, ck = bi % 49;
  int b = bt >> 2, t = bt & 3;
  int hw0 = ck * 64;
  int tid = threadIdx.x;
  int slot = tid & 15, c2 = tid >> 4;
  int p4 = slot * 4;

  // issue x loads EARLY (independent of the pre-transpose) so HBM latency hides under staging
  float4 xv[2][2];
  size_t xb[2][2];
#pragma unroll
  for (int half = 0; half < 2; ++half) {
    int c0 = (c2 + half * 16) * 2;
    xb[half][0] = ((size_t)(b * 64 + c0) * 4 + t) * HWD + hw0 + p4;
    xb[half][1] = xb[half][0] + 4 * HWD;
    xv[half][0] = *reinterpret_cast<const float4*>(&x[xb[half][0]]);
    xv[half][1] = *reinterpret_cast<const float4*>(&x[xb[half][1]]);
  }

  const u32* src = reinterpret_cast<const u32*>(pre) + ((size_t)bt * HWD + hw0) * 32;
#pragma unroll
  for (int it = 0; it < 8; ++it) {
    int task = it * 256 + tid;
    int p = task >> 5, cu = task & 31;
    pt[cu][p] = src[p * 32 + cu];
  }
  __syncthreads();
  const float invN = 1.f / NTOT;
#pragma unroll
  for (int half = 0; half < 2; ++half) {
    int cp = c2 + half * 16;
    int c0 = cp * 2;
    float mu0 = stats[c0] * invN;
    float va0 = stats[64 + c0] * invN - mu0 * mu0;
    float s0 = rsqrtf(va0 + 1e-5f) * gamma[c0];
    float h0 = beta[c0] - mu0 * s0;
    float mu1 = stats[c0 + 1] * invN;
    float va1 = stats[64 + c0 + 1] * invN - mu1 * mu1;
    float s1 = rsqrtf(va1 + 1e-5f) * gamma[c0 + 1];
    float h1 = beta[c0 + 1] - mu1 * s1;
    uint4 pv = *reinterpret_cast<const uint4*>(&pt[cp][p4]);
    float4 x0v = xv[half][0], x1v = xv[half][1];
    float4 o0, o1;
    o0.x = x0v.x + bf_lo(pv.x) * s0 + h0;  o1.x = x1v.x + bf_hi(pv.x) * s1 + h1;
    o0.y = x0v.y + bf_lo(pv.y) * s0 + h0;  o1.y = x1v.y + bf_hi(pv.y) * s1 + h1;
    o0.z = x0v.z + bf_lo(pv.z) * s0 + h0;  o1.z = x1v.z + bf_hi(pv.z) * s1 + h1;
    o0.w = x0v.w + bf_lo(pv.w) * s0 + h0;  o1.w = x1v.w + bf_hi(pv.w) * s1 + h1;
    *reinterpret_cast<float4*>(&out[xb[half][0]]) = o0;
    *reinterpret_cast<float4*>(&out[xb[half][1]]) = o1;
  }
}

extern "C" void kernel_launch(void* const* d_in, const int* in_sizes, int n_in,
                              void* d_out, int out_size, void* d_ws, size_t ws_size,
                              hipStream_t stream) {
  const float* x = (const float*)d_in[0];
  const float* w_in = (const float*)d_in[1];
  const float* b_in = (const float*)d_in[2];
  const float* w_out = (const float*)d_in[3];
  const float* b_out = (const float*)d_in[4];
  const float* gamma = (const float*)d_in[5];
  const float* beta = (const float*)d_in[6];
  float* out = (float*)d_out;

  const size_t NE = (size_t)BB * TT * HWD * 64;        // th/ph/pre
  const size_t NG = (size_t)BB * 64 * TT * GPLANE;     // padded g2
  u16* th = (u16*)d_ws;
  u16* ph = th + NE;
  u16* g2 = ph + NE;
  u16* pre = g2 + NG;
  float* stats = (float*)(pre + NE);

  k_conv_in<<<dim3(BB * TT * 49), dim3(256), 0, stream>>>(x, w_in, b_in, th, ph, g2, stats);
  k_attn<<<dim3(BB * 196), dim3(512), 0, stream>>>(th, ph, g2, w_out, b_out, pre);
  k_stats<<<dim3(392), dim3(256), 0, stream>>>(pre, stats);
  k_final<<<dim3(BB * TT * 49), dim3(256), 0, stream>>>(x, pre, stats, gamma, beta, out);
}

// Round 15
// 74.289 us; speedup vs baseline: 1.6253x; 1.0451x over previous
//
#include <hip/hip_runtime.h>

// LocalAttention collapsed form, all-MFMA edition.
// folded[c,t,Y] = (1/36) sum_{c'} theta[c',t,Y] * sum_d cnt(d,Y) sum_r phi[c',r,Y+d]*g[c,r,Y+d]
// This round: pre stored CHANNEL-MAJOR [b][c][t][hw] directly from k_attn's phase-C epilogue
// (scalar u16 stores, L2-coalesced per XCD) -> k_final is a pure elementwise stream (no LDS
// transpose) and k_stats is a contiguous per-channel reduce. k_attn phases A/B unchanged.

typedef unsigned short u16;
typedef unsigned int u32;
using f32x4 = __attribute__((ext_vector_type(4))) float;
using bf16x8 = __attribute__((ext_vector_type(8))) short;

#define BB 8
#define TT 4
#define HH 56
#define HWD 3136
#define GROW 64          // padded g2 row length (u16)
#define GPLANE 3584      // 56*64 per (b,c,rho)
#define NTOT 100352.0f

__device__ __forceinline__ float bf_lo(u32 u) { return __uint_as_float(u << 16); }
__device__ __forceinline__ float bf_hi(u32 u) { return __uint_as_float(u & 0xffff0000u); }
__device__ __forceinline__ float bf16u(u16 u) { return __uint_as_float(((u32)u) << 16); }
__device__ __forceinline__ u16 f2bf(float f) {
  u32 u = __float_as_uint(f);
  u32 r = (u + 0x7fffu + ((u >> 16) & 1u)) >> 16;
  return (u16)r;
}
__device__ __forceinline__ u32 pack2(float a, float b) {
  return (u32)f2bf(a) | ((u32)f2bf(b) << 16);
}
__device__ __forceinline__ int imax(int a, int b) { return a > b ? a : b; }
__device__ __forceinline__ int imin(int a, int b) { return a < b ? a : b; }
__device__ __forceinline__ float cntf(int d, int p) {
  int lo = imax(-1, imax(-1 - d, p - (HH - 1)));
  int hi = imin(1, imin(1 - d, p));
  int n = hi - lo + 1;
  return n > 0 ? (float)n : 0.f;
}

// ---------------- K1: conv_in as bf16 MFMA GEMM (XCD-pinned: image b -> XCD b) ----------------
#define K1_XOFF 24576
__global__ __launch_bounds__(256, 4) void k_conv_in(const float* __restrict__ x,
                                                    const float* __restrict__ w_in,
                                                    const float* __restrict__ b_in,
                                                    u16* __restrict__ th, u16* __restrict__ ph,
                                                    u16* __restrict__ g2, float* __restrict__ stats) {
  __shared__ __align__(16) char sm[24576 + 8192];
  if (blockIdx.x == 0 && threadIdx.x < 128) stats[threadIdx.x] = 0.f;
  int bi0 = blockIdx.x;
  int bi = (bi0 & 7) * 196 + (bi0 >> 3);  // XCD k owns image b=k (1568 = 8*196)
  int bt = bi / 49, chunk = bi % 49;
  int b = bt >> 2, t = bt & 3;
  int p0 = chunk * 64;
  int tid = threadIdx.x;

#pragma unroll
  for (int it = 0; it < 12; ++it) {
    int task = it * 256 + tid;
    int o = task >> 4, c4 = (task & 15) * 4;
    float4 wv = *reinterpret_cast<const float4*>(&w_in[o * 64 + c4]);
    uint2 pv;
    pv.x = pack2(wv.x, wv.y);
    pv.y = pack2(wv.z, wv.w);
    *reinterpret_cast<uint2*>(sm + o * 128 + ((c4 * 2) ^ ((o & 7) << 4))) = pv;
  }
  const float* xb = x + ((size_t)b * 256 + t) * HWD + p0;
#pragma unroll
  for (int it = 0; it < 2; ++it) {
    int task = it * 256 + tid;
    int cp = task >> 4, p4 = task & 15;
    int c0 = cp * 2;
    float4 fa = *reinterpret_cast<const float4*>(&xb[(size_t)c0 * 4 * HWD + p4 * 4]);
    float4 fb = *reinterpret_cast<const float4*>(&xb[(size_t)(c0 + 1) * 4 * HWD + p4 * 4]);
    float va[4] = {fa.x, fa.y, fa.z, fa.w}, vb[4] = {fb.x, fb.y, fb.z, fb.w};
#pragma unroll
    for (int j = 0; j < 4; ++j) {
      int p = p4 * 4 + j;
      int slot = (p & 7) ^ ((p >> 2) & 7);
      *reinterpret_cast<u32*>(sm + K1_XOFF + p * 128 + ((c0 * 2) ^ (slot << 4))) = pack2(va[j], vb[j]);
    }
  }
  __syncthreads();

  int w = tid >> 6, lane = tid & 63, lr = lane & 15, lk = lane >> 4;
  f32x4 acc[3][4];
#pragma unroll
  for (int i = 0; i < 3; ++i)
#pragma unroll
    for (int n = 0; n < 4; ++n) acc[i][n] = (f32x4){0.f, 0.f, 0.f, 0.f};

#pragma unroll
  for (int kt = 0; kt < 2; ++kt) {
    bf16x8 af[3], bfr[4];
#pragma unroll
    for (int i = 0; i < 3; ++i) {
      int arow = (w * 3 + i) * 16 + lr;
      af[i] = *reinterpret_cast<const bf16x8*>(sm + arow * 128 + ((kt * 64 + lk * 16) ^ ((arow & 7) << 4)));
    }
#pragma unroll
    for (int n = 0; n < 4; ++n) {
      int brow = n * 16 + lr;
      int slot = (brow & 7) ^ ((brow >> 2) & 7);
      bfr[n] = *reinterpret_cast<const bf16x8*>(sm + K1_XOFF + brow * 128 + ((kt * 64 + lk * 16) ^ (slot << 4)));
    }
#pragma unroll
    for (int i = 0; i < 3; ++i)
#pragma unroll
      for (int n = 0; n < 4; ++n)
        acc[i][n] = __builtin_amdgcn_mfma_f32_16x16x32_bf16(af[i], bfr[n], acc[i][n], 0, 0, 0);
  }

#pragma unroll
  for (int i = 0; i < 3; ++i) {
    int mt = w * 3 + i;
    int ob = mt * 16 + lk * 4;
    int gsel = ob >> 6, o = ob & 63;
    float4 bv = *reinterpret_cast<const float4*>(&b_in[ob]);
    if (gsel < 2) {
      u16* og = gsel == 0 ? th : ph;
#pragma unroll
      for (int n = 0; n < 4; ++n) {
        int p = p0 + n * 16 + lr;
        f32x4 a = acc[i][n];
        uint2 v;
        v.x = pack2(a.x + bv.x, a.y + bv.y);
        v.y = pack2(a.z + bv.z, a.w + bv.w);
        *reinterpret_cast<uint2*>(&og[((size_t)bt * HWD + p) * 64 + o]) = v;
      }
    } else {
      // g: padded layout [b][c][t(rho)][y][64], xx = x + 2
      float bb[4] = {bv.x, bv.y, bv.z, bv.w};
      int y0p = p0 / 56;
      int rel0 = p0 - y0p * 56;
#pragma unroll
      for (int n = 0; n < 4; ++n) {
        f32x4 a = acc[i][n];
        float aa[4] = {a.x, a.y, a.z, a.w};
        int rel = rel0 + n * 16 + lr;           // <= 111
        int cnd = rel >= 56;
        int off = (y0p + cnd) * GROW + (rel - (cnd ? 56 : 0)) + 2;
#pragma unroll
        for (int r = 0; r < 4; ++r)
          g2[(((size_t)b * 64 + o + r) * 4 + t) * GPLANE + off] = f2bf(aa[r] + bb[r]);
      }
    }
  }
}

// ---------------- K2: MFMA attention (staged structure; phase-C writes channel-major) ----------------
#define PH_OFF 0
#define AS_OFF 0
#define G_OFF 32768
#define W_OFF 32768
#define TH_OFF 65536
#define FOLD_OFF 65536
#define TAB_OFF 73728

__global__ __launch_bounds__(512, 4) void k_attn(const u16* __restrict__ th, const u16* __restrict__ ph,
                                                 const u16* __restrict__ g2,
                                                 const float* __restrict__ w_out,
                                                 const float* __restrict__ b_out,
                                                 u16* __restrict__ pre) {
  __shared__ __align__(16) char sm[73984];

  // XCD-chunked swizzle: 1568 = 8*196 -> XCD k owns image b=k; halo re-reads are L2-local.
  int bi0 = blockIdx.x;
  int bi = (bi0 & 7) * 196 + (bi0 >> 3);
  int b = bi / 196, tile = bi % 196;
  int ty = tile / 14, tx = tile % 14;
  int y0 = ty * 4, x0 = tx * 4;
  int tid = threadIdx.x;
  int w = tid >> 6, lane = tid & 63;
  int lr = lane & 15, lk = lane >> 4;

  // stage phi: rows (rho,Z), cols c, swizzled
  for (int task = tid; task < 2048; task += 512) {
    int row = task >> 3, ch = task & 7;
    int rho = row >> 6, Z = row & 63, zy = Z >> 3, zx = Z & 7;
    int Y = y0 - 2 + zy, X = x0 - 2 + zx;
    uint4 v = make_uint4(0, 0, 0, 0);
    if ((unsigned)Y < HH && (unsigned)X < HH)
      v = *reinterpret_cast<const uint4*>(&ph[(((size_t)b * 4 + rho) * HWD + Y * HH + X) * 64 + ch * 8]);
    *reinterpret_cast<uint4*>(sm + PH_OFF + row * 128 + ((ch * 16) ^ ((row & 7) << 4))) = v;
  }
  // stage theta: rows (pos,tau)
  {
    int row = tid >> 3, ch = tid & 7;
    int pos = row >> 2, tau = row & 3;
    int Y = y0 + (pos >> 2), X = x0 + (pos & 3);
    uint4 v = *reinterpret_cast<const uint4*>(&th[(((size_t)b * 4 + tau) * HWD + Y * HH + X) * 64 + ch * 8]);
    *reinterpret_cast<uint4*>(sm + TH_OFF + row * 128 + ((ch * 16) ^ ((row & 7) << 4))) = v;
  }
  // stage g (padded layout): per (c,rho,zy) one aligned 16B chunk via 2x dwordx2
  for (int task = tid; task < 2048; task += 512) {
    int c = task >> 5, rho = (task >> 3) & 3, zy = task & 7;
    int Y = y0 - 2 + zy;
    uint2 lo = make_uint2(0, 0), hi = make_uint2(0, 0);
    if ((unsigned)Y < HH) {
      const u16* gb = g2 + (((size_t)b * 64 + c) * 4 + rho) * GPLANE + Y * GROW + x0;  // xx0 = (x0-2)+2
      lo = *reinterpret_cast<const uint2*>(gb);
      hi = *reinterpret_cast<const uint2*>(gb + 4);
    }
    uint4 v = make_uint4(lo.x, lo.y, hi.x, hi.y);
    *reinterpret_cast<uint4*>(sm + G_OFF + c * 512 + ((16 * (rho * 8 + zy)) ^ ((c & 7) << 4))) = v;
  }
  // cnt tables (1/36 folded into cyt)
  if (tid < 32) {
    int zy = tid >> 2, py = tid & 3;
    reinterpret_cast<float*>(sm + TAB_OFF)[tid] = cntf(zy - 2 - py, y0 + py) * (1.f / 36.f);
  } else if (tid < 64) {
    int i = tid - 32;
    int zx = i >> 2, px = i & 3;
    reinterpret_cast<float*>(sm + TAB_OFF + 128)[i] = cntf(zx - 2 - px, x0 + px);
  }
  __syncthreads();

  // ---- Phase A: D[(rho,Z)][(pos,tau)] = phi . theta ----
  bf16x8 tb[4][2];
#pragma unroll
  for (int nt = 0; nt < 4; ++nt)
#pragma unroll
    for (int kt = 0; kt < 2; ++kt) {
      int row = nt * 16 + lr;
      tb[nt][kt] = *reinterpret_cast<const bf16x8*>(sm + TH_OFF + row * 128 + ((kt * 64 + lk * 16) ^ ((row & 7) << 4)));
    }
  f32x4 accA[2][4];
#pragma unroll
  for (int mi = 0; mi < 2; ++mi)
#pragma unroll
    for (int nt = 0; nt < 4; ++nt) accA[mi][nt] = (f32x4){0.f, 0.f, 0.f, 0.f};
  __builtin_amdgcn_s_setprio(1);
#pragma unroll
  for (int mi = 0; mi < 2; ++mi) {
    int mt = w * 2 + mi;
    int mrow = mt * 16 + lr;
    int p2 = (2 * mt) & 7;  // zy-pair start of this m-tile
#pragma unroll
    for (int kt = 0; kt < 2; ++kt) {
      bf16x8 af = *reinterpret_cast<const bf16x8*>(sm + PH_OFF + mrow * 128 + ((kt * 64 + lk * 16) ^ ((mrow & 7) << 4)));
#pragma unroll
      for (int nt = 0; nt < 4; ++nt) {
        if ((p2 == 0 && nt >= 2) || (p2 == 6 && nt < 2)) continue;  // cnt_y == 0 block
        accA[mi][nt] = __builtin_amdgcn_mfma_f32_16x16x32_bf16(af, tb[nt][kt], accA[mi][nt], 0, 0, 0);
      }
    }
  }
  __builtin_amdgcn_s_setprio(0);
  __syncthreads();  // phi reads done; As may overwrite

  // ---- Phase A epilogue: scale by cnt (py=nt, px=lr>>2), write As[(pos,tau)][(rho,Z)] ----
  {
    const float* cyt = reinterpret_cast<const float*>(sm + TAB_OFF);
    const float* cxt = reinterpret_cast<const float*>(sm + TAB_OFF + 128);
    int px = lr >> 2;
#pragma unroll
    for (int mi = 0; mi < 2; ++mi) {
      int mbase = (w * 2 + mi) * 16 + lk * 4;
      int zy = (mbase >> 3) & 7;
      int zxb = mbase & 7;  // 0 or 4
      float cxv[4];
#pragma unroll
      for (int r = 0; r < 4; ++r) cxv[r] = cxt[(zxb + r) * 4 + px];
#pragma unroll
      for (int nt = 0; nt < 4; ++nt) {
        int n = nt * 16 + lr;
        float cyv = cyt[zy * 4 + nt];
        f32x4 a = accA[mi][nt];
        uint2 vv;
        vv.x = pack2(a.x * cyv * cxv[0], a.y * cyv * cxv[1]);
        vv.y = pack2(a.z * cyv * cxv[2], a.w * cyv * cxv[3]);
        *reinterpret_cast<uint2*>(sm + AS_OFF + n * 512 + ((mbase * 2) ^ ((n & 7) << 4))) = vv;
      }
    }
  }
  __syncthreads();  // As ready

  // ---- Phase B: folded[(pos,tau)][c] = As * g ----
  int mtB = w & 3, ntb = (w >> 2) * 2;
  f32x4 accB[2];
  accB[0] = (f32x4){0.f, 0.f, 0.f, 0.f};
  accB[1] = (f32x4){0.f, 0.f, 0.f, 0.f};
  {
    int arow = mtB * 16 + lr;
    __builtin_amdgcn_s_setprio(1);
#pragma unroll
    for (int kt = 0; kt < 8; ++kt) {
      bf16x8 af = *reinterpret_cast<const bf16x8*>(sm + AS_OFF + arow * 512 + ((kt * 64 + lk * 16) ^ ((arow & 7) << 4)));
#pragma unroll
      for (int j = 0; j < 2; ++j) {
        int brow = (ntb + j) * 16 + lr;
        bf16x8 bfv = *reinterpret_cast<const bf16x8*>(sm + G_OFF + brow * 512 + ((kt * 64 + lk * 16) ^ ((brow & 7) << 4)));
        accB[j] = __builtin_amdgcn_mfma_f32_16x16x32_bf16(af, bfv, accB[j], 0, 0, 0);
      }
    }
    __builtin_amdgcn_s_setprio(0);
  }
  __syncthreads();  // g reads done; w_s may overwrite

  // ---- write folded (bf16) + stage w_out ----
#pragma unroll
  for (int j = 0; j < 2; ++j) {
    int n = (ntb + j) * 16 + lr;
#pragma unroll
    for (int r = 0; r < 4; ++r) {
      int m = mtB * 16 + lk * 4 + r;
      *reinterpret_cast<u16*>(sm + FOLD_OFF + m * 128 + ((n * 2) ^ ((m & 7) << 4))) = f2bf(accB[j][r]);
    }
  }
  {
    int o = tid >> 3, cg = tid & 7;
    float4 w0 = *reinterpret_cast<const float4*>(&w_out[o * 64 + cg * 8]);
    float4 w1 = *reinterpret_cast<const float4*>(&w_out[o * 64 + cg * 8 + 4]);
    uint4 wv = make_uint4(pack2(w0.x, w0.y), pack2(w0.z, w0.w), pack2(w1.x, w1.y), pack2(w1.z, w1.w));
    *reinterpret_cast<uint4*>(sm + W_OFF + o * 128 + ((cg * 16) ^ ((o & 7) << 4))) = wv;
  }
  __syncthreads();

  // ---- Phase C: pre[b][o][tau][hw] = W . fold^T (channel-major scatter; L2 coalesces) ----
  int mtC = w & 3, ntc = (w >> 2) * 2;
  f32x4 accC[2];
  accC[0] = (f32x4){0.f, 0.f, 0.f, 0.f};
  accC[1] = (f32x4){0.f, 0.f, 0.f, 0.f};
  {
    int arow = mtC * 16 + lr;
    __builtin_amdgcn_s_setprio(1);
#pragma unroll
    for (int kt = 0; kt < 2; ++kt) {
      bf16x8 af = *reinterpret_cast<const bf16x8*>(sm + W_OFF + arow * 128 + ((kt * 64 + lk * 16) ^ ((arow & 7) << 4)));
#pragma unroll
      for (int j = 0; j < 2; ++j) {
        int brow = (ntc + j) * 16 + lr;
        bf16x8 bfv = *reinterpret_cast<const bf16x8*>(sm + FOLD_OFF + brow * 128 + ((kt * 64 + lk * 16) ^ ((brow & 7) << 4)));
        accC[j] = __builtin_amdgcn_mfma_f32_16x16x32_bf16(af, bfv, accC[j], 0, 0, 0);
      }
    }
    __builtin_amdgcn_s_setprio(0);
  }
  {
    int o4 = mtC * 16 + lk * 4;
    float4 bo = *reinterpret_cast<const float4*>(&b_out[o4]);
    float bof[4] = {bo.x, bo.y, bo.z, bo.w};
#pragma unroll
    for (int j = 0; j < 2; ++j) {
      int n = (ntc + j) * 16 + lr;
      int pos = n >> 2, tau = n & 3;
      int hw = (y0 + (pos >> 2)) * HH + x0 + (pos & 3);
      float av[4] = {accC[j].x, accC[j].y, accC[j].z, accC[j].w};
#pragma unroll
      for (int r = 0; r < 4; ++r)
        pre[((size_t)(b * 64 + o4 + r) * 4 + tau) * HWD + hw] = f2bf(av[r] + bof[r]);
    }
  }
}

// ---------------- K3: per-channel sum/sumsq, contiguous reads (block = one (b,c) chunk) ----------------
__global__ __launch_bounds__(256) void k_stats(const u16* __restrict__ pre, float* __restrict__ stats) {
  __shared__ float rs[4], rq[4];
  int tid = threadIdx.x;
  int b = blockIdx.x & 7, c = blockIdx.x >> 3;  // XCD b reads image b's chunk (L2-local)
  const uint4* p = reinterpret_cast<const uint4*>(pre + (size_t)(b * 64 + c) * 4 * HWD);
  float s = 0.f, q = 0.f;
#pragma unroll
  for (int j = 0; j < 7; ++j) {
    int idx = j * 256 + tid;
    if (idx < 1568) {  // 12544 u16 = 1568 uint4 per (b,c)
      uint4 v = p[idx];
      u32 uu[4] = {v.x, v.y, v.z, v.w};
#pragma unroll
      for (int k = 0; k < 4; ++k) {
        float a = bf_lo(uu[k]), d = bf_hi(uu[k]);
        s += a + d;
        q += a * a + d * d;
      }
    }
  }
#pragma unroll
  for (int off = 32; off; off >>= 1) {
    s += __shfl_down(s, off);
    q += __shfl_down(q, off);
  }
  if ((tid & 63) == 0) { rs[tid >> 6] = s; rq[tid >> 6] = q; }
  __syncthreads();
  if (tid == 0) {
    float ts = rs[0] + rs[1] + rs[2] + rs[3];
    float tq = rq[0] + rq[1] + rq[2] + rq[3];
    atomicAdd(&stats[c], ts);
    atomicAdd(&stats[64 + c], tq);
  }
}

// ---------------- K4: BN finalize + residual — pure elementwise stream (pre layout == out) ----------------
__global__ __launch_bounds__(256) void k_final(const float* __restrict__ x, const u16* __restrict__ pre,
                                               const float* __restrict__ stats,
                                               const float* __restrict__ gamma,
                                               const float* __restrict__ beta,
                                               float* __restrict__ out) {
  int bi0 = blockIdx.x;
  int bi = (bi0 & 7) * 392 + (bi0 >> 3);  // 3136 = 8*392; XCD k streams image b=k
  size_t i8 = ((size_t)bi * 256 + threadIdx.x) * 8;
  int c = (int)((i8 / 12544) & 63);       // 12544 = 4*HWD elements per (b,c)
  const float invN = 1.f / NTOT;
  float mu = stats[c] * invN;
  float var = stats[64 + c] * invN - mu * mu;
  float s = rsqrtf(var + 1e-5f) * gamma[c];
  float h = beta[c] - mu * s;
  uint4 pv = *reinterpret_cast<const uint4*>(&pre[i8]);
  float4 xa = *reinterpret_cast<const float4*>(&x[i8]);
  float4 xbv = *reinterpret_cast<const float4*>(&x[i8 + 4]);
  float4 o0, o1;
  o0.x = xa.x + bf_lo(pv.x) * s + h;   o0.y = xa.y + bf_hi(pv.x) * s + h;
  o0.z = xa.z + bf_lo(pv.y) * s + h;   o0.w = xa.w + bf_hi(pv.y) * s + h;
  o1.x = xbv.x + bf_lo(pv.z) * s + h;  o1.y = xbv.y + bf_hi(pv.z) * s + h;
  o1.z = xbv.z + bf_lo(pv.w) * s + h;  o1.w = xbv.w + bf_hi(pv.w) * s + h;
  *reinterpret_cast<float4*>(&out[i8]) = o0;
  *reinterpret_cast<float4*>(&out[i8 + 4]) = o1;
}

extern "C" void kernel_launch(void* const* d_in, const int* in_sizes, int n_in,
                              void* d_out, int out_size, void* d_ws, size_t ws_size,
                              hipStream_t stream) {
  const float* x = (const float*)d_in[0];
  const float* w_in = (const float*)d_in[1];
  const float* b_in = (const float*)d_in[2];
  const float* w_out = (const float*)d_in[3];
  const float* b_out = (const float*)d_in[4];
  const float* gamma = (const float*)d_in[5];
  const float* beta = (const float*)d_in[6];
  float* out = (float*)d_out;

  const size_t NE = (size_t)BB * TT * HWD * 64;        // th/ph/pre
  const size_t NG = (size_t)BB * 64 * TT * GPLANE;     // padded g2
  u16* th = (u16*)d_ws;
  u16* ph = th + NE;
  u16* g2 = ph + NE;
  u16* pre = g2 + NG;
  float* stats = (float*)(pre + NE);

  k_conv_in<<<dim3(BB * TT * 49), dim3(256), 0, stream>>>(x, w_in, b_in, th, ph, g2, stats);
  k_attn<<<dim3(BB * 196), dim3(512), 0, stream>>>(th, ph, g2, w_out, b_out, pre);
  k_stats<<<dim3(512), dim3(256), 0, stream>>>(pre, stats);
  k_final<<<dim3(3136), dim3(256), 0, stream>>>(x, pre, stats, gamma, beta, out);
}

// Round 16
// 74.251 us; speedup vs baseline: 1.6261x; 1.0005x over previous
//
#include <hip/hip_runtime.h>

// LocalAttention collapsed form, all-MFMA edition.
// folded[c,t,Y] = (1/36) sum_{c'} theta[c',t,Y] * sum_d cnt(d,Y) sum_r phi[c',r,Y+d]*g[c,r,Y+d]
// This round: phase-B K reordered zy-major (k' = zy*32+rho*8+zx) so the 3/8 zy-slices with
// cnt_y==0 are skipped as whole MFMA kt-groups (16->10 MFMA, 24->15 ds_read per wave in B).
// pre stays channel-major; k_final pure stream; k_stats contiguous reduce.

typedef unsigned short u16;
typedef unsigned int u32;
using f32x4 = __attribute__((ext_vector_type(4))) float;
using bf16x8 = __attribute__((ext_vector_type(8))) short;

#define BB 8
#define TT 4
#define HH 56
#define HWD 3136
#define GROW 64          // padded g2 row length (u16)
#define GPLANE 3584      // 56*64 per (b,c,rho)
#define NTOT 100352.0f

__device__ __forceinline__ float bf_lo(u32 u) { return __uint_as_float(u << 16); }
__device__ __forceinline__ float bf_hi(u32 u) { return __uint_as_float(u & 0xffff0000u); }
__device__ __forceinline__ float bf16u(u16 u) { return __uint_as_float(((u32)u) << 16); }
__device__ __forceinline__ u16 f2bf(float f) {
  u32 u = __float_as_uint(f);
  u32 r = (u + 0x7fffu + ((u >> 16) & 1u)) >> 16;
  return (u16)r;
}
__device__ __forceinline__ u32 pack2(float a, float b) {
  return (u32)f2bf(a) | ((u32)f2bf(b) << 16);
}
__device__ __forceinline__ int imax(int a, int b) { return a > b ? a : b; }
__device__ __forceinline__ int imin(int a, int b) { return a < b ? a : b; }
__device__ __forceinline__ float cntf(int d, int p) {
  int lo = imax(-1, imax(-1 - d, p - (HH - 1)));
  int hi = imin(1, imin(1 - d, p));
  int n = hi - lo + 1;
  return n > 0 ? (float)n : 0.f;
}

// ---------------- K1: conv_in as bf16 MFMA GEMM (XCD-pinned: image b -> XCD b) ----------------
#define K1_XOFF 24576
__global__ __launch_bounds__(256, 4) void k_conv_in(const float* __restrict__ x,
                                                    const float* __restrict__ w_in,
                                                    const float* __restrict__ b_in,
                                                    u16* __restrict__ th, u16* __restrict__ ph,
                                                    u16* __restrict__ g2, float* __restrict__ stats) {
  __shared__ __align__(16) char sm[24576 + 8192];
  if (blockIdx.x == 0 && threadIdx.x < 128) stats[threadIdx.x] = 0.f;
  int bi0 = blockIdx.x;
  int bi = (bi0 & 7) * 196 + (bi0 >> 3);  // XCD k owns image b=k (1568 = 8*196)
  int bt = bi / 49, chunk = bi % 49;
  int b = bt >> 2, t = bt & 3;
  int p0 = chunk * 64;
  int tid = threadIdx.x;

#pragma unroll
  for (int it = 0; it < 12; ++it) {
    int task = it * 256 + tid;
    int o = task >> 4, c4 = (task & 15) * 4;
    float4 wv = *reinterpret_cast<const float4*>(&w_in[o * 64 + c4]);
    uint2 pv;
    pv.x = pack2(wv.x, wv.y);
    pv.y = pack2(wv.z, wv.w);
    *reinterpret_cast<uint2*>(sm + o * 128 + ((c4 * 2) ^ ((o & 7) << 4))) = pv;
  }
  const float* xb = x + ((size_t)b * 256 + t) * HWD + p0;
#pragma unroll
  for (int it = 0; it < 2; ++it) {
    int task = it * 256 + tid;
    int cp = task >> 4, p4 = task & 15;
    int c0 = cp * 2;
    float4 fa = *reinterpret_cast<const float4*>(&xb[(size_t)c0 * 4 * HWD + p4 * 4]);
    float4 fb = *reinterpret_cast<const float4*>(&xb[(size_t)(c0 + 1) * 4 * HWD + p4 * 4]);
    float va[4] = {fa.x, fa.y, fa.z, fa.w}, vb[4] = {fb.x, fb.y, fb.z, fb.w};
#pragma unroll
    for (int j = 0; j < 4; ++j) {
      int p = p4 * 4 + j;
      int slot = (p & 7) ^ ((p >> 2) & 7);
      *reinterpret_cast<u32*>(sm + K1_XOFF + p * 128 + ((c0 * 2) ^ (slot << 4))) = pack2(va[j], vb[j]);
    }
  }
  __syncthreads();

  int w = tid >> 6, lane = tid & 63, lr = lane & 15, lk = lane >> 4;
  f32x4 acc[3][4];
#pragma unroll
  for (int i = 0; i < 3; ++i)
#pragma unroll
    for (int n = 0; n < 4; ++n) acc[i][n] = (f32x4){0.f, 0.f, 0.f, 0.f};

#pragma unroll
  for (int kt = 0; kt < 2; ++kt) {
    bf16x8 af[3], bfr[4];
#pragma unroll
    for (int i = 0; i < 3; ++i) {
      int arow = (w * 3 + i) * 16 + lr;
      af[i] = *reinterpret_cast<const bf16x8*>(sm + arow * 128 + ((kt * 64 + lk * 16) ^ ((arow & 7) << 4)));
    }
#pragma unroll
    for (int n = 0; n < 4; ++n) {
      int brow = n * 16 + lr;
      int slot = (brow & 7) ^ ((brow >> 2) & 7);
      bfr[n] = *reinterpret_cast<const bf16x8*>(sm + K1_XOFF + brow * 128 + ((kt * 64 + lk * 16) ^ (slot << 4)));
    }
#pragma unroll
    for (int i = 0; i < 3; ++i)
#pragma unroll
      for (int n = 0; n < 4; ++n)
        acc[i][n] = __builtin_amdgcn_mfma_f32_16x16x32_bf16(af[i], bfr[n], acc[i][n], 0, 0, 0);
  }

#pragma unroll
  for (int i = 0; i < 3; ++i) {
    int mt = w * 3 + i;
    int ob = mt * 16 + lk * 4;
    int gsel = ob >> 6, o = ob & 63;
    float4 bv = *reinterpret_cast<const float4*>(&b_in[ob]);
    if (gsel < 2) {
      u16* og = gsel == 0 ? th : ph;
#pragma unroll
      for (int n = 0; n < 4; ++n) {
        int p = p0 + n * 16 + lr;
        f32x4 a = acc[i][n];
        uint2 v;
        v.x = pack2(a.x + bv.x, a.y + bv.y);
        v.y = pack2(a.z + bv.z, a.w + bv.w);
        *reinterpret_cast<uint2*>(&og[((size_t)bt * HWD + p) * 64 + o]) = v;
      }
    } else {
      // g: padded layout [b][c][t(rho)][y][64], xx = x + 2
      float bb[4] = {bv.x, bv.y, bv.z, bv.w};
      int y0p = p0 / 56;
      int rel0 = p0 - y0p * 56;
#pragma unroll
      for (int n = 0; n < 4; ++n) {
        f32x4 a = acc[i][n];
        float aa[4] = {a.x, a.y, a.z, a.w};
        int rel = rel0 + n * 16 + lr;           // <= 111
        int cnd = rel >= 56;
        int off = (y0p + cnd) * GROW + (rel - (cnd ? 56 : 0)) + 2;
#pragma unroll
        for (int r = 0; r < 4; ++r)
          g2[(((size_t)b * 64 + o + r) * 4 + t) * GPLANE + off] = f2bf(aa[r] + bb[r]);
      }
    }
  }
}

// ---------------- K2: MFMA attention (zy-major K in phase B; channel-major pre writes) ----------------
#define PH_OFF 0
#define AS_OFF 0
#define G_OFF 32768
#define W_OFF 32768
#define TH_OFF 65536
#define FOLD_OFF 65536
#define TAB_OFF 73728

__global__ __launch_bounds__(512, 4) void k_attn(const u16* __restrict__ th, const u16* __restrict__ ph,
                                                 const u16* __restrict__ g2,
                                                 const float* __restrict__ w_out,
                                                 const float* __restrict__ b_out,
                                                 u16* __restrict__ pre) {
  __shared__ __align__(16) char sm[73984];

  // XCD-chunked swizzle: 1568 = 8*196 -> XCD k owns image b=k; halo re-reads are L2-local.
  int bi0 = blockIdx.x;
  int bi = (bi0 & 7) * 196 + (bi0 >> 3);
  int b = bi / 196, tile = bi % 196;
  int ty = tile / 14, tx = tile % 14;
  int y0 = ty * 4, x0 = tx * 4;
  int tid = threadIdx.x;
  int w = tid >> 6, lane = tid & 63;
  int lr = lane & 15, lk = lane >> 4;

  // stage phi: rows (rho,Z), cols c, swizzled
  for (int task = tid; task < 2048; task += 512) {
    int row = task >> 3, ch = task & 7;
    int rho = row >> 6, Z = row & 63, zy = Z >> 3, zx = Z & 7;
    int Y = y0 - 2 + zy, X = x0 - 2 + zx;
    uint4 v = make_uint4(0, 0, 0, 0);
    if ((unsigned)Y < HH && (unsigned)X < HH)
      v = *reinterpret_cast<const uint4*>(&ph[(((size_t)b * 4 + rho) * HWD + Y * HH + X) * 64 + ch * 8]);
    *reinterpret_cast<uint4*>(sm + PH_OFF + row * 128 + ((ch * 16) ^ ((row & 7) << 4))) = v;
  }
  // stage theta: rows (pos,tau)
  {
    int row = tid >> 3, ch = tid & 7;
    int pos = row >> 2, tau = row & 3;
    int Y = y0 + (pos >> 2), X = x0 + (pos & 3);
    uint4 v = *reinterpret_cast<const uint4*>(&th[(((size_t)b * 4 + tau) * HWD + Y * HH + X) * 64 + ch * 8]);
    *reinterpret_cast<uint4*>(sm + TH_OFF + row * 128 + ((ch * 16) ^ ((row & 7) << 4))) = v;
  }
  // stage g (padded layout): per (c,rho,zy) one aligned 16B chunk; columns zy-major (zy*64+rho*16)
  for (int task = tid; task < 2048; task += 512) {
    int c = task >> 5, rho = (task >> 3) & 3, zy = task & 7;
    int Y = y0 - 2 + zy;
    uint2 lo = make_uint2(0, 0), hi = make_uint2(0, 0);
    if ((unsigned)Y < HH) {
      const u16* gb = g2 + (((size_t)b * 64 + c) * 4 + rho) * GPLANE + Y * GROW + x0;  // xx0 = (x0-2)+2
      lo = *reinterpret_cast<const uint2*>(gb);
      hi = *reinterpret_cast<const uint2*>(gb + 4);
    }
    uint4 v = make_uint4(lo.x, lo.y, hi.x, hi.y);
    *reinterpret_cast<uint4*>(sm + G_OFF + c * 512 + ((zy * 64 + rho * 16) ^ ((c & 7) << 4))) = v;
  }
  // cnt tables (1/36 folded into cyt)
  if (tid < 32) {
    int zy = tid >> 2, py = tid & 3;
    reinterpret_cast<float*>(sm + TAB_OFF)[tid] = cntf(zy - 2 - py, y0 + py) * (1.f / 36.f);
  } else if (tid < 64) {
    int i = tid - 32;
    int zx = i >> 2, px = i & 3;
    reinterpret_cast<float*>(sm + TAB_OFF + 128)[i] = cntf(zx - 2 - px, x0 + px);
  }
  __syncthreads();

  // ---- Phase A: D[(rho,Z)][(pos,tau)] = phi . theta ----
  bf16x8 tb[4][2];
#pragma unroll
  for (int nt = 0; nt < 4; ++nt)
#pragma unroll
    for (int kt = 0; kt < 2; ++kt) {
      int row = nt * 16 + lr;
      tb[nt][kt] = *reinterpret_cast<const bf16x8*>(sm + TH_OFF + row * 128 + ((kt * 64 + lk * 16) ^ ((row & 7) << 4)));
    }
  f32x4 accA[2][4];
#pragma unroll
  for (int mi = 0; mi < 2; ++mi)
#pragma unroll
    for (int nt = 0; nt < 4; ++nt) accA[mi][nt] = (f32x4){0.f, 0.f, 0.f, 0.f};
  __builtin_amdgcn_s_setprio(1);
#pragma unroll
  for (int mi = 0; mi < 2; ++mi) {
    int mt = w * 2 + mi;
    int mrow = mt * 16 + lr;
    int p2 = (2 * mt) & 7;  // zy-pair start of this m-tile
#pragma unroll
    for (int kt = 0; kt < 2; ++kt) {
      bf16x8 af = *reinterpret_cast<const bf16x8*>(sm + PH_OFF + mrow * 128 + ((kt * 64 + lk * 16) ^ ((mrow & 7) << 4)));
#pragma unroll
      for (int nt = 0; nt < 4; ++nt) {
        if ((p2 == 0 && nt >= 2) || (p2 == 6 && nt < 2)) continue;  // cnt_y == 0 block
        accA[mi][nt] = __builtin_amdgcn_mfma_f32_16x16x32_bf16(af, tb[nt][kt], accA[mi][nt], 0, 0, 0);
      }
    }
  }
  __builtin_amdgcn_s_setprio(0);
  __syncthreads();  // phi reads done; As may overwrite

  // ---- Phase A epilogue: scale by cnt; write As[(pos,tau)][k'=zy*32+rho*8+zx] (zy-major) ----
  {
    const float* cyt = reinterpret_cast<const float*>(sm + TAB_OFF);
    const float* cxt = reinterpret_cast<const float*>(sm + TAB_OFF + 128);
    int px = lr >> 2;
#pragma unroll
    for (int mi = 0; mi < 2; ++mi) {
      int mbase = (w * 2 + mi) * 16 + lk * 4;
      int rho = mbase >> 6;
      int zy = (mbase >> 3) & 7;
      int zxb = mbase & 7;  // 0 or 4
      int colb = zy * 32 + rho * 8 + zxb;  // zy-major column base (4 consecutive)
      float cxv[4];
#pragma unroll
      for (int r = 0; r < 4; ++r) cxv[r] = cxt[(zxb + r) * 4 + px];
#pragma unroll
      for (int nt = 0; nt < 4; ++nt) {
        int n = nt * 16 + lr;
        float cyv = cyt[zy * 4 + nt];
        f32x4 a = accA[mi][nt];
        uint2 vv;
        vv.x = pack2(a.x * cyv * cxv[0], a.y * cyv * cxv[1]);
        vv.y = pack2(a.z * cyv * cxv[2], a.w * cyv * cxv[3]);
        *reinterpret_cast<uint2*>(sm + AS_OFF + n * 512 + ((colb * 2) ^ ((n & 7) << 4))) = vv;
      }
    }
  }
  __syncthreads();  // As ready

  // ---- Phase B: folded[(pos,tau)][c] = As * g ; kt == zy, skip cnt_y==0 slices ----
  int mtB = w & 3, ntb = (w >> 2) * 2;
  f32x4 accB[2];
  accB[0] = (f32x4){0.f, 0.f, 0.f, 0.f};
  accB[1] = (f32x4){0.f, 0.f, 0.f, 0.f};
  {
    int arow = mtB * 16 + lr;
    __builtin_amdgcn_s_setprio(1);
#pragma unroll
    for (int kt = 0; kt < 8; ++kt) {
      // rows of this m-tile all have py = mtB; zy=kt contributes only if kt in [mtB, mtB+4]
      if (kt < mtB || kt > mtB + 4) continue;
      bf16x8 af = *reinterpret_cast<const bf16x8*>(sm + AS_OFF + arow * 512 + ((kt * 64 + lk * 16) ^ ((arow & 7) << 4)));
#pragma unroll
      for (int j = 0; j < 2; ++j) {
        int brow = (ntb + j) * 16 + lr;
        bf16x8 bfv = *reinterpret_cast<const bf16x8*>(sm + G_OFF + brow * 512 + ((kt * 64 + lk * 16) ^ ((brow & 7) << 4)));
        accB[j] = __builtin_amdgcn_mfma_f32_16x16x32_bf16(af, bfv, accB[j], 0, 0, 0);
      }
    }
    __builtin_amdgcn_s_setprio(0);
  }
  __syncthreads();  // g reads done; w_s may overwrite

  // ---- write folded (bf16) + stage w_out ----
#pragma unroll
  for (int j = 0; j < 2; ++j) {
    int n = (ntb + j) * 16 + lr;
#pragma unroll
    for (int r = 0; r < 4; ++r) {
      int m = mtB * 16 + lk * 4 + r;
      *reinterpret_cast<u16*>(sm + FOLD_OFF + m * 128 + ((n * 2) ^ ((m & 7) << 4))) = f2bf(accB[j][r]);
    }
  }
  {
    int o = tid >> 3, cg = tid & 7;
    float4 w0 = *reinterpret_cast<const float4*>(&w_out[o * 64 + cg * 8]);
    float4 w1 = *reinterpret_cast<const float4*>(&w_out[o * 64 + cg * 8 + 4]);
    uint4 wv = make_uint4(pack2(w0.x, w0.y), pack2(w0.z, w0.w), pack2(w1.x, w1.y), pack2(w1.z, w1.w));
    *reinterpret_cast<uint4*>(sm + W_OFF + o * 128 + ((cg * 16) ^ ((o & 7) << 4))) = wv;
  }
  __syncthreads();

  // ---- Phase C: pre[b][o][tau][hw] = W . fold^T (channel-major scatter; L2 coalesces) ----
  int mtC = w & 3, ntc = (w >> 2) * 2;
  f32x4 accC[2];
  accC[0] = (f32x4){0.f, 0.f, 0.f, 0.f};
  accC[1] = (f32x4){0.f, 0.f, 0.f, 0.f};
  {
    int arow = mtC * 16 + lr;
    __builtin_amdgcn_s_setprio(1);
#pragma unroll
    for (int kt = 0; kt < 2; ++kt) {
      bf16x8 af = *reinterpret_cast<const bf16x8*>(sm + W_OFF + arow * 128 + ((kt * 64 + lk * 16) ^ ((arow & 7) << 4)));
#pragma unroll
      for (int j = 0; j < 2; ++j) {
        int brow = (ntc + j) * 16 + lr;
        bf16x8 bfv = *reinterpret_cast<const bf16x8*>(sm + FOLD_OFF + brow * 128 + ((kt * 64 + lk * 16) ^ ((brow & 7) << 4)));
        accC[j] = __builtin_amdgcn_mfma_f32_16x16x32_bf16(af, bfv, accC[j], 0, 0, 0);
      }
    }
    __builtin_amdgcn_s_setprio(0);
  }
  {
    int o4 = mtC * 16 + lk * 4;
    float4 bo = *reinterpret_cast<const float4*>(&b_out[o4]);
    float bof[4] = {bo.x, bo.y, bo.z, bo.w};
#pragma unroll
    for (int j = 0; j < 2; ++j) {
      int n = (ntc + j) * 16 + lr;
      int pos = n >> 2, tau = n & 3;
      int hw = (y0 + (pos >> 2)) * HH + x0 + (pos & 3);
      float av[4] = {accC[j].x, accC[j].y, accC[j].z, accC[j].w};
#pragma unroll
      for (int r = 0; r < 4; ++r)
        pre[((size_t)(b * 64 + o4 + r) * 4 + tau) * HWD + hw] = f2bf(av[r] + bof[r]);
    }
  }
}

// ---------------- K3: per-channel sum/sumsq, contiguous reads (block = one (b,c) chunk) ----------------
__global__ __launch_bounds__(256) void k_stats(const u16* __restrict__ pre, float* __restrict__ stats) {
  __shared__ float rs[4], rq[4];
  int tid = threadIdx.x;
  int b = blockIdx.x & 7, c = blockIdx.x >> 3;  // XCD b reads image b's chunk (L2-local)
  const uint4* p = reinterpret_cast<const uint4*>(pre + (size_t)(b * 64 + c) * 4 * HWD);
  float s = 0.f, q = 0.f;
#pragma unroll
  for (int j = 0; j < 7; ++j) {
    int idx = j * 256 + tid;
    if (idx < 1568) {  // 12544 u16 = 1568 uint4 per (b,c)
      uint4 v = p[idx];
      u32 uu[4] = {v.x, v.y, v.z, v.w};
#pragma unroll
      for (int k = 0; k < 4; ++k) {
        float a = bf_lo(uu[k]), d = bf_hi(uu[k]);
        s += a + d;
        q += a * a + d * d;
      }
    }
  }
#pragma unroll
  for (int off = 32; off; off >>= 1) {
    s += __shfl_down(s, off);
    q += __shfl_down(q, off);
  }
  if ((tid & 63) == 0) { rs[tid >> 6] = s; rq[tid >> 6] = q; }
  __syncthreads();
  if (tid == 0) {
    float ts = rs[0] + rs[1] + rs[2] + rs[3];
    float tq = rq[0] + rq[1] + rq[2] + rq[3];
    atomicAdd(&stats[c], ts);
    atomicAdd(&stats[64 + c], tq);
  }
}

// ---------------- K4: BN finalize + residual — pure elementwise stream (pre layout == out) ----------------
__global__ __launch_bounds__(256) void k_final(const float* __restrict__ x, const u16* __restrict__ pre,
                                               const float* __restrict__ stats,
                                               const float* __restrict__ gamma,
                                               const float* __restrict__ beta,
                                               float* __restrict__ out) {
  int bi0 = blockIdx.x;
  int bi = (bi0 & 7) * 392 + (bi0 >> 3);  // 3136 = 8*392; XCD k streams image b=k
  size_t i8 = ((size_t)bi * 256 + threadIdx.x) * 8;
  int c = (int)((i8 / 12544) & 63);       // 12544 = 4*HWD elements per (b,c)
  const float invN = 1.f / NTOT;
  float mu = stats[c] * invN;
  float var = stats[64 + c] * invN - mu * mu;
  float s = rsqrtf(var + 1e-5f) * gamma[c];
  float h = beta[c] - mu * s;
  uint4 pv = *reinterpret_cast<const uint4*>(&pre[i8]);
  float4 xa = *reinterpret_cast<const float4*>(&x[i8]);
  float4 xbv = *reinterpret_cast<const float4*>(&x[i8 + 4]);
  float4 o0, o1;
  o0.x = xa.x + bf_lo(pv.x) * s + h;   o0.y = xa.y + bf_hi(pv.x) * s + h;
  o0.z = xa.z + bf_lo(pv.y) * s + h;   o0.w = xa.w + bf_hi(pv.y) * s + h;
  o1.x = xbv.x + bf_lo(pv.z) * s + h;  o1.y = xbv.y + bf_hi(pv.z) * s + h;
  o1.z = xbv.z + bf_lo(pv.w) * s + h;  o1.w = xbv.w + bf_hi(pv.w) * s + h;
  *reinterpret_cast<float4*>(&out[i8]) = o0;
  *reinterpret_cast<float4*>(&out[i8 + 4]) = o1;
}

extern "C" void kernel_launch(void* const* d_in, const int* in_sizes, int n_in,
                              void* d_out, int out_size, void* d_ws, size_t ws_size,
                              hipStream_t stream) {
  const float* x = (const float*)d_in[0];
  const float* w_in = (const float*)d_in[1];
  const float* b_in = (const float*)d_in[2];
  const float* w_out = (const float*)d_in[3];
  const float* b_out = (const float*)d_in[4];
  const float* gamma = (const float*)d_in[5];
  const float* beta = (const float*)d_in[6];
  float* out = (float*)d_out;

  const size_t NE = (size_t)BB * TT * HWD * 64;        // th/ph/pre
  const size_t NG = (size_t)BB * 64 * TT * GPLANE;     // padded g2
  u16* th = (u16*)d_ws;
  u16* ph = th + NE;
  u16* g2 = ph + NE;
  u16* pre = g2 + NG;
  float* stats = (float*)(pre + NE);

  k_conv_in<<<dim3(BB * TT * 49), dim3(256), 0, stream>>>(x, w_in, b_in, th, ph, g2, stats);
  k_attn<<<dim3(BB * 196), dim3(512), 0, stream>>>(th, ph, g2, w_out, b_out, pre);
  k_stats<<<dim3(512), dim3(256), 0, stream>>>(pre, stats);
  k_final<<<dim3(3136), dim3(256), 0, stream>>>(x, pre, stats, gamma, beta, out);
}

// Round 18
// 74.169 us; speedup vs baseline: 1.6279x; 1.0011x over previous
//
#include <hip/hip_runtime.h>

// LocalAttention collapsed form, all-MFMA edition. (Final: round-15 best-known build, 74.25 us.)
// folded[c,t,Y] = (1/36) sum_{c'} theta[c',t,Y] * sum_d cnt(d,Y) sum_r phi[c',r,Y+d]*g[c,r,Y+d]
// - K1 conv_in as bf16 MFMA GEMM, XCD-pinned (image b -> XCD b); g stored padded channel-major.
// - K2 staged MFMA attention: phi/th/g -> LDS (XOR-swizzled), A=phi.theta (cnt_y==0 m-tiles
//   skipped), cnt-scale epilogue, B=As.g with zy-major K + zy-slice skip, C=W.fold^T writing
//   pre CHANNEL-MAJOR (scattered u16, coalesced in XCD-local L2).
// - K3 contiguous per-channel reduce; K4 pure elementwise BN+residual stream.

typedef unsigned short u16;
typedef unsigned int u32;
using f32x4 = __attribute__((ext_vector_type(4))) float;
using bf16x8 = __attribute__((ext_vector_type(8))) short;

#define BB 8
#define TT 4
#define HH 56
#define HWD 3136
#define GROW 64          // padded g2 row length (u16)
#define GPLANE 3584      // 56*64 per (b,c,rho)
#define NTOT 100352.0f

__device__ __forceinline__ float bf_lo(u32 u) { return __uint_as_float(u << 16); }
__device__ __forceinline__ float bf_hi(u32 u) { return __uint_as_float(u & 0xffff0000u); }
__device__ __forceinline__ float bf16u(u16 u) { return __uint_as_float(((u32)u) << 16); }
__device__ __forceinline__ u16 f2bf(float f) {
  u32 u = __float_as_uint(f);
  u32 r = (u + 0x7fffu + ((u >> 16) & 1u)) >> 16;
  return (u16)r;
}
__device__ __forceinline__ u32 pack2(float a, float b) {
  return (u32)f2bf(a) | ((u32)f2bf(b) << 16);
}
__device__ __forceinline__ int imax(int a, int b) { return a > b ? a : b; }
__device__ __forceinline__ int imin(int a, int b) { return a < b ? a : b; }
__device__ __forceinline__ float cntf(int d, int p) {
  int lo = imax(-1, imax(-1 - d, p - (HH - 1)));
  int hi = imin(1, imin(1 - d, p));
  int n = hi - lo + 1;
  return n > 0 ? (float)n : 0.f;
}

// ---------------- K1: conv_in as bf16 MFMA GEMM (XCD-pinned: image b -> XCD b) ----------------
#define K1_XOFF 24576
__global__ __launch_bounds__(256, 4) void k_conv_in(const float* __restrict__ x,
                                                    const float* __restrict__ w_in,
                                                    const float* __restrict__ b_in,
                                                    u16* __restrict__ th, u16* __restrict__ ph,
                                                    u16* __restrict__ g2, float* __restrict__ stats) {
  __shared__ __align__(16) char sm[24576 + 8192];
  if (blockIdx.x == 0 && threadIdx.x < 128) stats[threadIdx.x] = 0.f;
  int bi0 = blockIdx.x;
  int bi = (bi0 & 7) * 196 + (bi0 >> 3);  // XCD k owns image b=k (1568 = 8*196)
  int bt = bi / 49, chunk = bi % 49;
  int b = bt >> 2, t = bt & 3;
  int p0 = chunk * 64;
  int tid = threadIdx.x;

#pragma unroll
  for (int it = 0; it < 12; ++it) {
    int task = it * 256 + tid;
    int o = task >> 4, c4 = (task & 15) * 4;
    float4 wv = *reinterpret_cast<const float4*>(&w_in[o * 64 + c4]);
    uint2 pv;
    pv.x = pack2(wv.x, wv.y);
    pv.y = pack2(wv.z, wv.w);
    *reinterpret_cast<uint2*>(sm + o * 128 + ((c4 * 2) ^ ((o & 7) << 4))) = pv;
  }
  const float* xb = x + ((size_t)b * 256 + t) * HWD + p0;
#pragma unroll
  for (int it = 0; it < 2; ++it) {
    int task = it * 256 + tid;
    int cp = task >> 4, p4 = task & 15;
    int c0 = cp * 2;
    float4 fa = *reinterpret_cast<const float4*>(&xb[(size_t)c0 * 4 * HWD + p4 * 4]);
    float4 fb = *reinterpret_cast<const float4*>(&xb[(size_t)(c0 + 1) * 4 * HWD + p4 * 4]);
    float va[4] = {fa.x, fa.y, fa.z, fa.w}, vb[4] = {fb.x, fb.y, fb.z, fb.w};
#pragma unroll
    for (int j = 0; j < 4; ++j) {
      int p = p4 * 4 + j;
      int slot = (p & 7) ^ ((p >> 2) & 7);
      *reinterpret_cast<u32*>(sm + K1_XOFF + p * 128 + ((c0 * 2) ^ (slot << 4))) = pack2(va[j], vb[j]);
    }
  }
  __syncthreads();

  int w = tid >> 6, lane = tid & 63, lr = lane & 15, lk = lane >> 4;
  f32x4 acc[3][4];
#pragma unroll
  for (int i = 0; i < 3; ++i)
#pragma unroll
    for (int n = 0; n < 4; ++n) acc[i][n] = (f32x4){0.f, 0.f, 0.f, 0.f};

#pragma unroll
  for (int kt = 0; kt < 2; ++kt) {
    bf16x8 af[3], bfr[4];
#pragma unroll
    for (int i = 0; i < 3; ++i) {
      int arow = (w * 3 + i) * 16 + lr;
      af[i] = *reinterpret_cast<const bf16x8*>(sm + arow * 128 + ((kt * 64 + lk * 16) ^ ((arow & 7) << 4)));
    }
#pragma unroll
    for (int n = 0; n < 4; ++n) {
      int brow = n * 16 + lr;
      int slot = (brow & 7) ^ ((brow >> 2) & 7);
      bfr[n] = *reinterpret_cast<const bf16x8*>(sm + K1_XOFF + brow * 128 + ((kt * 64 + lk * 16) ^ (slot << 4)));
    }
#pragma unroll
    for (int i = 0; i < 3; ++i)
#pragma unroll
      for (int n = 0; n < 4; ++n)
        acc[i][n] = __builtin_amdgcn_mfma_f32_16x16x32_bf16(af[i], bfr[n], acc[i][n], 0, 0, 0);
  }

#pragma unroll
  for (int i = 0; i < 3; ++i) {
    int mt = w * 3 + i;
    int ob = mt * 16 + lk * 4;
    int gsel = ob >> 6, o = ob & 63;
    float4 bv = *reinterpret_cast<const float4*>(&b_in[ob]);
    if (gsel < 2) {
      u16* og = gsel == 0 ? th : ph;
#pragma unroll
      for (int n = 0; n < 4; ++n) {
        int p = p0 + n * 16 + lr;
        f32x4 a = acc[i][n];
        uint2 v;
        v.x = pack2(a.x + bv.x, a.y + bv.y);
        v.y = pack2(a.z + bv.z, a.w + bv.w);
        *reinterpret_cast<uint2*>(&og[((size_t)bt * HWD + p) * 64 + o]) = v;
      }
    } else {
      // g: padded layout [b][c][t(rho)][y][64], xx = x + 2
      float bb[4] = {bv.x, bv.y, bv.z, bv.w};
      int y0p = p0 / 56;
      int rel0 = p0 - y0p * 56;
#pragma unroll
      for (int n = 0; n < 4; ++n) {
        f32x4 a = acc[i][n];
        float aa[4] = {a.x, a.y, a.z, a.w};
        int rel = rel0 + n * 16 + lr;           // <= 111
        int cnd = rel >= 56;
        int off = (y0p + cnd) * GROW + (rel - (cnd ? 56 : 0)) + 2;
#pragma unroll
        for (int r = 0; r < 4; ++r)
          g2[(((size_t)b * 64 + o + r) * 4 + t) * GPLANE + off] = f2bf(aa[r] + bb[r]);
      }
    }
  }
}

// ---------------- K2: MFMA attention (zy-major K in phase B; channel-major pre writes) ----------------
#define PH_OFF 0
#define AS_OFF 0
#define G_OFF 32768
#define W_OFF 32768
#define TH_OFF 65536
#define FOLD_OFF 65536
#define TAB_OFF 73728

__global__ __launch_bounds__(512, 4) void k_attn(const u16* __restrict__ th, const u16* __restrict__ ph,
                                                 const u16* __restrict__ g2,
                                                 const float* __restrict__ w_out,
                                                 const float* __restrict__ b_out,
                                                 u16* __restrict__ pre) {
  __shared__ __align__(16) char sm[73984];

  // XCD-chunked swizzle: 1568 = 8*196 -> XCD k owns image b=k; halo re-reads are L2-local.
  int bi0 = blockIdx.x;
  int bi = (bi0 & 7) * 196 + (bi0 >> 3);
  int b = bi / 196, tile = bi % 196;
  int ty = tile / 14, tx = tile % 14;
  int y0 = ty * 4, x0 = tx * 4;
  int tid = threadIdx.x;
  int w = tid >> 6, lane = tid & 63;
  int lr = lane & 15, lk = lane >> 4;

  // stage phi: rows (rho,Z), cols c, swizzled
  for (int task = tid; task < 2048; task += 512) {
    int row = task >> 3, ch = task & 7;
    int rho = row >> 6, Z = row & 63, zy = Z >> 3, zx = Z & 7;
    int Y = y0 - 2 + zy, X = x0 - 2 + zx;
    uint4 v = make_uint4(0, 0, 0, 0);
    if ((unsigned)Y < HH && (unsigned)X < HH)
      v = *reinterpret_cast<const uint4*>(&ph[(((size_t)b * 4 + rho) * HWD + Y * HH + X) * 64 + ch * 8]);
    *reinterpret_cast<uint4*>(sm + PH_OFF + row * 128 + ((ch * 16) ^ ((row & 7) << 4))) = v;
  }
  // stage theta: rows (pos,tau)
  {
    int row = tid >> 3, ch = tid & 7;
    int pos = row >> 2, tau = row & 3;
    int Y = y0 + (pos >> 2), X = x0 + (pos & 3);
    uint4 v = *reinterpret_cast<const uint4*>(&th[(((size_t)b * 4 + tau) * HWD + Y * HH + X) * 64 + ch * 8]);
    *reinterpret_cast<uint4*>(sm + TH_OFF + row * 128 + ((ch * 16) ^ ((row & 7) << 4))) = v;
  }
  // stage g (padded layout): per (c,rho,zy) one aligned 16B chunk; columns zy-major (zy*64+rho*16)
  for (int task = tid; task < 2048; task += 512) {
    int c = task >> 5, rho = (task >> 3) & 3, zy = task & 7;
    int Y = y0 - 2 + zy;
    uint2 lo = make_uint2(0, 0), hi = make_uint2(0, 0);
    if ((unsigned)Y < HH) {
      const u16* gb = g2 + (((size_t)b * 64 + c) * 4 + rho) * GPLANE + Y * GROW + x0;  // xx0 = (x0-2)+2
      lo = *reinterpret_cast<const uint2*>(gb);
      hi = *reinterpret_cast<const uint2*>(gb + 4);
    }
    uint4 v = make_uint4(lo.x, lo.y, hi.x, hi.y);
    *reinterpret_cast<uint4*>(sm + G_OFF + c * 512 + ((zy * 64 + rho * 16) ^ ((c & 7) << 4))) = v;
  }
  // cnt tables (1/36 folded into cyt)
  if (tid < 32) {
    int zy = tid >> 2, py = tid & 3;
    reinterpret_cast<float*>(sm + TAB_OFF)[tid] = cntf(zy - 2 - py, y0 + py) * (1.f / 36.f);
  } else if (tid < 64) {
    int i = tid - 32;
    int zx = i >> 2, px = i & 3;
    reinterpret_cast<float*>(sm + TAB_OFF + 128)[i] = cntf(zx - 2 - px, x0 + px);
  }
  __syncthreads();

  // ---- Phase A: D[(rho,Z)][(pos,tau)] = phi . theta ----
  bf16x8 tb[4][2];
#pragma unroll
  for (int nt = 0; nt < 4; ++nt)
#pragma unroll
    for (int kt = 0; kt < 2; ++kt) {
      int row = nt * 16 + lr;
      tb[nt][kt] = *reinterpret_cast<const bf16x8*>(sm + TH_OFF + row * 128 + ((kt * 64 + lk * 16) ^ ((row & 7) << 4)));
    }
  f32x4 accA[2][4];
#pragma unroll
  for (int mi = 0; mi < 2; ++mi)
#pragma unroll
    for (int nt = 0; nt < 4; ++nt) accA[mi][nt] = (f32x4){0.f, 0.f, 0.f, 0.f};
  __builtin_amdgcn_s_setprio(1);
#pragma unroll
  for (int mi = 0; mi < 2; ++mi) {
    int mt = w * 2 + mi;
    int mrow = mt * 16 + lr;
    int p2 = (2 * mt) & 7;  // zy-pair start of this m-tile
#pragma unroll
    for (int kt = 0; kt < 2; ++kt) {
      bf16x8 af = *reinterpret_cast<const bf16x8*>(sm + PH_OFF + mrow * 128 + ((kt * 64 + lk * 16) ^ ((mrow & 7) << 4)));
#pragma unroll
      for (int nt = 0; nt < 4; ++nt) {
        if ((p2 == 0 && nt >= 2) || (p2 == 6 && nt < 2)) continue;  // cnt_y == 0 block
        accA[mi][nt] = __builtin_amdgcn_mfma_f32_16x16x32_bf16(af, tb[nt][kt], accA[mi][nt], 0, 0, 0);
      }
    }
  }
  __builtin_amdgcn_s_setprio(0);
  __syncthreads();  // phi reads done; As may overwrite

  // ---- Phase A epilogue: scale by cnt; write As[(pos,tau)][k'=zy*32+rho*8+zx] (zy-major) ----
  {
    const float* cyt = reinterpret_cast<const float*>(sm + TAB_OFF);
    const float* cxt = reinterpret_cast<const float*>(sm + TAB_OFF + 128);
    int px = lr >> 2;
#pragma unroll
    for (int mi = 0; mi < 2; ++mi) {
      int mbase = (w * 2 + mi) * 16 + lk * 4;
      int rho = mbase >> 6;
      int zy = (mbase >> 3) & 7;
      int zxb = mbase & 7;  // 0 or 4
      int colb = zy * 32 + rho * 8 + zxb;  // zy-major column base (4 consecutive)
      float cxv[4];
#pragma unroll
      for (int r = 0; r < 4; ++r) cxv[r] = cxt[(zxb + r) * 4 + px];
#pragma unroll
      for (int nt = 0; nt < 4; ++nt) {
        int n = nt * 16 + lr;
        float cyv = cyt[zy * 4 + nt];
        f32x4 a = accA[mi][nt];
        uint2 vv;
        vv.x = pack2(a.x * cyv * cxv[0], a.y * cyv * cxv[1]);
        vv.y = pack2(a.z * cyv * cxv[2], a.w * cyv * cxv[3]);
        *reinterpret_cast<uint2*>(sm + AS_OFF + n * 512 + ((colb * 2) ^ ((n & 7) << 4))) = vv;
      }
    }
  }
  __syncthreads();  // As ready

  // ---- Phase B: folded[(pos,tau)][c] = As * g ; kt == zy, skip cnt_y==0 slices ----
  int mtB = w & 3, ntb = (w >> 2) * 2;
  f32x4 accB[2];
  accB[0] = (f32x4){0.f, 0.f, 0.f, 0.f};
  accB[1] = (f32x4){0.f, 0.f, 0.f, 0.f};
  {
    int arow = mtB * 16 + lr;
    __builtin_amdgcn_s_setprio(1);
#pragma unroll
    for (int kt = 0; kt < 8; ++kt) {
      // rows of this m-tile all have py = mtB; zy=kt contributes only if kt in [mtB, mtB+4]
      if (kt < mtB || kt > mtB + 4) continue;
      bf16x8 af = *reinterpret_cast<const bf16x8*>(sm + AS_OFF + arow * 512 + ((kt * 64 + lk * 16) ^ ((arow & 7) << 4)));
#pragma unroll
      for (int j = 0; j < 2; ++j) {
        int brow = (ntb + j) * 16 + lr;
        bf16x8 bfv = *reinterpret_cast<const bf16x8*>(sm + G_OFF + brow * 512 + ((kt * 64 + lk * 16) ^ ((brow & 7) << 4)));
        accB[j] = __builtin_amdgcn_mfma_f32_16x16x32_bf16(af, bfv, accB[j], 0, 0, 0);
      }
    }
    __builtin_amdgcn_s_setprio(0);
  }
  __syncthreads();  // g reads done; w_s may overwrite

  // ---- write folded (bf16) + stage w_out ----
#pragma unroll
  for (int j = 0; j < 2; ++j) {
    int n = (ntb + j) * 16 + lr;
#pragma unroll
    for (int r = 0; r < 4; ++r) {
      int m = mtB * 16 + lk * 4 + r;
      *reinterpret_cast<u16*>(sm + FOLD_OFF + m * 128 + ((n * 2) ^ ((m & 7) << 4))) = f2bf(accB[j][r]);
    }
  }
  {
    int o = tid >> 3, cg = tid & 7;
    float4 w0 = *reinterpret_cast<const float4*>(&w_out[o * 64 + cg * 8]);
    float4 w1 = *reinterpret_cast<const float4*>(&w_out[o * 64 + cg * 8 + 4]);
    uint4 wv = make_uint4(pack2(w0.x, w0.y), pack2(w0.z, w0.w), pack2(w1.x, w1.y), pack2(w1.z, w1.w));
    *reinterpret_cast<uint4*>(sm + W_OFF + o * 128 + ((cg * 16) ^ ((o & 7) << 4))) = wv;
  }
  __syncthreads();

  // ---- Phase C: pre[b][o][tau][hw] = W . fold^T (channel-major scatter; L2 coalesces) ----
  int mtC = w & 3, ntc = (w >> 2) * 2;
  f32x4 accC[2];
  accC[0] = (f32x4){0.f, 0.f, 0.f, 0.f};
  accC[1] = (f32x4){0.f, 0.f, 0.f, 0.f};
  {
    int arow = mtC * 16 + lr;
    __builtin_amdgcn_s_setprio(1);
#pragma unroll
    for (int kt = 0; kt < 2; ++kt) {
      bf16x8 af = *reinterpret_cast<const bf16x8*>(sm + W_OFF + arow * 128 + ((kt * 64 + lk * 16) ^ ((arow & 7) << 4)));
#pragma unroll
      for (int j = 0; j < 2; ++j) {
        int brow = (ntc + j) * 16 + lr;
        bf16x8 bfv = *reinterpret_cast<const bf16x8*>(sm + FOLD_OFF + brow * 128 + ((kt * 64 + lk * 16) ^ ((brow & 7) << 4)));
        accC[j] = __builtin_amdgcn_mfma_f32_16x16x32_bf16(af, bfv, accC[j], 0, 0, 0);
      }
    }
    __builtin_amdgcn_s_setprio(0);
  }
  {
    int o4 = mtC * 16 + lk * 4;
    float4 bo = *reinterpret_cast<const float4*>(&b_out[o4]);
    float bof[4] = {bo.x, bo.y, bo.z, bo.w};
#pragma unroll
    for (int j = 0; j < 2; ++j) {
      int n = (ntc + j) * 16 + lr;
      int pos = n >> 2, tau = n & 3;
      int hw = (y0 + (pos >> 2)) * HH + x0 + (pos & 3);
      float av[4] = {accC[j].x, accC[j].y, accC[j].z, accC[j].w};
#pragma unroll
      for (int r = 0; r < 4; ++r)
        pre[((size_t)(b * 64 + o4 + r) * 4 + tau) * HWD + hw] = f2bf(av[r] + bof[r]);
    }
  }
}

// ---------------- K3: per-channel sum/sumsq, contiguous reads (block = one (b,c) chunk) ----------------
__global__ __launch_bounds__(256) void k_stats(const u16* __restrict__ pre, float* __restrict__ stats) {
  __shared__ float rs[4], rq[4];
  int tid = threadIdx.x;
  int b = blockIdx.x & 7, c = blockIdx.x >> 3;  // XCD b reads image b's chunk (L2-local)
  const uint4* p = reinterpret_cast<const uint4*>(pre + (size_t)(b * 64 + c) * 4 * HWD);
  float s = 0.f, q = 0.f;
#pragma unroll
  for (int j = 0; j < 7; ++j) {
    int idx = j * 256 + tid;
    if (idx < 1568) {  // 12544 u16 = 1568 uint4 per (b,c)
      uint4 v = p[idx];
      u32 uu[4] = {v.x, v.y, v.z, v.w};
#pragma unroll
      for (int k = 0; k < 4; ++k) {
        float a = bf_lo(uu[k]), d = bf_hi(uu[k]);
        s += a + d;
        q += a * a + d * d;
      }
    }
  }
#pragma unroll
  for (int off = 32; off; off >>= 1) {
    s += __shfl_down(s, off);
    q += __shfl_down(q, off);
  }
  if ((tid & 63) == 0) { rs[tid >> 6] = s; rq[tid >> 6] = q; }
  __syncthreads();
  if (tid == 0) {
    float ts = rs[0] + rs[1] + rs[2] + rs[3];
    float tq = rq[0] + rq[1] + rq[2] + rq[3];
    atomicAdd(&stats[c], ts);
    atomicAdd(&stats[64 + c], tq);
  }
}

// ---------------- K4: BN finalize + residual — pure elementwise stream (pre layout == out) ----------------
__global__ __launch_bounds__(256) void k_final(const float* __restrict__ x, const u16* __restrict__ pre,
                                               const float* __restrict__ stats,
                                               const float* __restrict__ gamma,
                                               const float* __restrict__ beta,
                                               float* __restrict__ out) {
  int bi0 = blockIdx.x;
  int bi = (bi0 & 7) * 392 + (bi0 >> 3);  // 3136 = 8*392; XCD k streams image b=k
  size_t i8 = ((size_t)bi * 256 + threadIdx.x) * 8;
  int c = (int)((i8 / 12544) & 63);       // 12544 = 4*HWD elements per (b,c)
  const float invN = 1.f / NTOT;
  float mu = stats[c] * invN;
  float var = stats[64 + c] * invN - mu * mu;
  float s = rsqrtf(var + 1e-5f) * gamma[c];
  float h = beta[c] - mu * s;
  uint4 pv = *reinterpret_cast<const uint4*>(&pre[i8]);
  float4 xa = *reinterpret_cast<const float4*>(&x[i8]);
  float4 xbv = *reinterpret_cast<const float4*>(&x[i8 + 4]);
  float4 o0, o1;
  o0.x = xa.x + bf_lo(pv.x) * s + h;   o0.y = xa.y + bf_hi(pv.x) * s + h;
  o0.z = xa.z + bf_lo(pv.y) * s + h;   o0.w = xa.w + bf_hi(pv.y) * s + h;
  o1.x = xbv.x + bf_lo(pv.z) * s + h;  o1.y = xbv.y + bf_hi(pv.z) * s + h;
  o1.z = xbv.z + bf_lo(pv.w) * s + h;  o1.w = xbv.w + bf_hi(pv.w) * s + h;
  *reinterpret_cast<float4*>(&out[i8]) = o0;
  *reinterpret_cast<float4*>(&out[i8 + 4]) = o1;
}

extern "C" void kernel_launch(void* const* d_in, const int* in_sizes, int n_in,
                              void* d_out, int out_size, void* d_ws, size_t ws_size,
                              hipStream_t stream) {
  const float* x = (const float*)d_in[0];
  const float* w_in = (const float*)d_in[1];
  const float* b_in = (const float*)d_in[2];
  const float* w_out = (const float*)d_in[3];
  const float* b_out = (const float*)d_in[4];
  const float* gamma = (const float*)d_in[5];
  const float* beta = (const float*)d_in[6];
  float* out = (float*)d_out;

  const size_t NE = (size_t)BB * TT * HWD * 64;        // th/ph/pre
  const size_t NG = (size_t)BB * 64 * TT * GPLANE;     // padded g2
  u16* th = (u16*)d_ws;
  u16* ph = th + NE;
  u16* g2 = ph + NE;
  u16* pre = g2 + NG;
  float* stats = (float*)(pre + NE);

  k_conv_in<<<dim3(BB * TT * 49), dim3(256), 0, stream>>>(x, w_in, b_in, th, ph, g2, stats);
  k_attn<<<dim3(BB * 196), dim3(512), 0, stream>>>(th, ph, g2, w_out, b_out, pre);
  k_stats<<<dim3(512), dim3(256), 0, stream>>>(pre, stats);
  k_final<<<dim3(3136), dim3(256), 0, stream>>>(x, pre, stats, gamma, beta, out);
}